// Round 12
// baseline (8012.052 us; speedup 1.0000x reference)
//
#include <hip/hip_runtime.h>
#include <hip/hip_bf16.h>
#include <math.h>

// ---------------- problem constants ----------------
#define NGRP 16     // one workgroup per batch element
#define NTHR 1024
#define TSEQ 48
#define DDIM 256
#define HDIM 32
#define NLAY 3
#define NOUT 6

// ---------------- ws layout ----------------
#define GRP_OFF   16384u
#define GRP_STRF  5120u          // floats per group block (precompute_ca output)
#define CAL_F  4096              // [3*256] cross-attn constants
#define WB_OFF 360448u           // bf16 weights (element offsets below)
#define WOFF_QKV 0u
#define WOFF_WO  589824u
#define WOFF_F1  786432u
#define WOFF_F2  1572864u
#define WOFF_OP1 2359296u
#define NCVT     2392064u
#define KV_OFF   5505024u        // fp32 KV cache: per group 2*3*48*256 floats

__device__ __forceinline__ void bfp(unsigned int u, float& lo, float& hi) {
  union { unsigned int i; float f; } a, b;
  a.i = u << 16; b.i = u & 0xffff0000u; lo = a.f; hi = b.f;
}
__device__ __forceinline__ float gelu_exact(float x) {
  return 0.5f * x * (1.0f + erff(x * 0.70710678118654752f));
}
__device__ __forceinline__ float dot8(const uint4& u, const float* x, int k0) {
  float lo, hi, acc = 0.f;
  bfp(u.x, lo, hi); acc += x[k0  ]*lo + x[k0+1]*hi;
  bfp(u.y, lo, hi); acc += x[k0+2]*lo + x[k0+3]*hi;
  bfp(u.z, lo, hi); acc += x[k0+4]*lo + x[k0+5]*hi;
  bfp(u.w, lo, hi); acc += x[k0+6]*lo + x[k0+7]*hi;
  return acc;
}

// ---------------- weight fp32 -> bf16 ----------------
__global__ void convert_bf16(const float* qkv, const float* ow, const float* f1,
                             const float* f2, const float* w1, unsigned char* ws) {
  __hip_bfloat16* dst = (__hip_bfloat16*)(ws + WB_OFF);
  size_t stride = (size_t)gridDim.x * blockDim.x;
  for (size_t i = (size_t)blockIdx.x * blockDim.x + threadIdx.x; i < NCVT; i += stride) {
    float v;
    if      (i < WOFF_WO)  v = qkv[i];
    else if (i < WOFF_F1)  v = ow[i - WOFF_WO];
    else if (i < WOFF_F2)  v = f1[i - WOFF_F1];
    else if (i < WOFF_OP1) v = f2[i - WOFF_F2];
    else                   v = w1[i - WOFF_OP1];
    dst[i] = __float2bfloat16(v);
  }
}

// ---------------- one-shot per-(g,l): memvec chain + cross-attn const ----------------
// cross-attn K/V rows identical over T -> softmax uniform -> out = V(memvec): constant.
__global__ void precompute_ca(const float* zs, const float* zk,
                              const float* mw1, const float* mb1,
                              const float* mlg, const float* mlb,
                              const float* mw2, const float* mb2,
                              const float* cqw, const float* cqb,
                              const float* cow, const float* cob,
                              unsigned char* ws) {
  const int g = blockIdx.x & 15, l = blockIdx.x >> 4;
  const int tid = threadIdx.x;           // 256 threads
  __shared__ float cond[128], h[256], mvv[256], vv[256], lred[16];

  auto lnstat = [&](float v, float& m, float& rs) {
    float a = v, b = v * v;
    #pragma unroll
    for (int off = 32; off; off >>= 1) { a += __shfl_xor(a, off); b += __shfl_xor(b, off); }
    if ((tid & 63) == 0) { lred[tid >> 6] = a; lred[4 + (tid >> 6)] = b; }
    __syncthreads();
    float sa = lred[0]+lred[1]+lred[2]+lred[3];
    float sb = lred[4]+lred[5]+lred[6]+lred[7];
    m = sa * (1.0f/256.0f);
    rs = rsqrtf(sb * (1.0f/256.0f) - m*m + 1e-5f);
    __syncthreads();
  };

  if (tid < 128) cond[tid] = (tid < 64) ? zs[g*64 + tid] : zk[g*64 + tid - 64];
  __syncthreads();
  float acc = mb1[tid];
  { const float* w = mw1 + (size_t)tid * 128;
    for (int k = 0; k < 128; k += 4) {
      float4 q = *(const float4*)(w + k);
      acc += q.x*cond[k] + q.y*cond[k+1] + q.z*cond[k+2] + q.w*cond[k+3];
    } }
  float m, rs; lnstat(acc, m, rs);
  h[tid] = gelu_exact((acc - m) * rs * mlg[tid] + mlb[tid]);
  __syncthreads();
  float a2 = mb2[tid];
  { const float* w = mw2 + (size_t)tid * 256;
    for (int k = 0; k < 256; k += 4) {
      float4 q = *(const float4*)(w + k);
      a2 += q.x*h[k] + q.y*h[k+1] + q.z*h[k+2] + q.w*h[k+3];
    } }
  mvv[tid] = a2;
  __syncthreads();
  float a3 = cqb[l*768 + 512 + tid];
  { const float* w = cqw + ((size_t)l*768 + 512 + tid) * 256;
    for (int k = 0; k < 256; k += 4) {
      float4 q = *(const float4*)(w + k);
      a3 += q.x*mvv[k] + q.y*mvv[k+1] + q.z*mvv[k+2] + q.w*mvv[k+3];
    } }
  vv[tid] = a3;
  __syncthreads();
  float a4 = cob[l*256 + tid];
  { const float* w = cow + ((size_t)l*256 + tid) * 256;
    for (int k = 0; k < 256; k += 4) {
      float4 q = *(const float4*)(w + k);
      a4 += q.x*vv[k] + q.y*vv[k+1] + q.z*vv[k+2] + q.w*vv[k+3];
    } }
  ((float*)(ws + GRP_OFF))[(size_t)g * GRP_STRF + CAL_F + l*256 + tid] = a4;
}

struct DecP {
  const float *start_token, *emb_w, *emb_b;
  const float *sa_qkv_b, *sa_o_b;
  const float *ln1_g, *ln1_b, *ln2_g, *ln2_b, *ln3_g, *ln3_b;
  const float *ff1_b, *ff2_b;
  const float *op_b1, *op_w2, *op_b2;
  float* out;
  unsigned char* ws;
};

// Single-WG-per-batch persistent decoder: 16 blocks x 1024 threads.
// ZERO inter-workgroup communication: all sync is __syncthreads over 16 waves.
// Weights read direct from global bf16 (16-wave TLP hides L2/LLC latency).
// KV cache in per-group global ws (fp32, L2-local: same WG writes and reads).
__global__ __launch_bounds__(NTHR, 4) void decoder_persistent(DecP p) {
  const int g = blockIdx.x;            // batch element 0..15
  const int tid = threadIdx.x;

  const float* CALW = (const float*)(p.ws + GRP_OFF) + (size_t)g * GRP_STRF + CAL_F;
  const unsigned short* WB = (const unsigned short*)(p.ws + WB_OFF);
  const unsigned short* WQKV = WB + WOFF_QKV;
  const unsigned short* WWO  = WB + WOFF_WO;
  const unsigned short* WF1  = WB + WOFF_F1;
  const unsigned short* WF2  = WB + WOFF_F2;
  const unsigned short* WOP1 = WB + WOFF_OP1;
  float* kg = (float*)(p.ws + KV_OFF) + (size_t)g * (2*NLAY*TSEQ*DDIM);
  float* vg = kg + NLAY*TSEQ*DDIM;

  __shared__ float xls[DDIM], x2ls[DDIM], lred[32], fxl[1024], obuf[DDIM], ffo[DDIM];
  __shared__ float qh[DDIM], ah[DDIM], sc[8*64];
  __shared__ float cals[768], obias[768], ff2b[768];
  __shared__ float ln1g[768], ln1b[768], ln2g[768], ln2b[768], ln3g[768], ln3b[768];
  __shared__ float qkvb[2304], ff1b[3072];
  __shared__ float embw[DDIM*NOUT], embb[DDIM];
  __shared__ float opb1[128], opw2[NOUT*128], opb2[8], OUTV[8];

  const int row4 = tid >> 2, kk = tid & 3;   // 4 threads per GEMV output row
  const int wv = tid >> 6, ln = tid & 63;    // wave id / lane id

  // ---- single-sync LN stats over 256 dims (values live in tid<256) ----
  auto lnstats = [&](float v, float* slot, float& m, float& rs) {
    float a = v, b = v * v;
    #pragma unroll
    for (int off = 32; off; off >>= 1) { a += __shfl_xor(a, off); b += __shfl_xor(b, off); }
    if ((tid & 63) == 0 && tid < 256) { slot[tid >> 6] = a; slot[4 + (tid >> 6)] = b; }
    __syncthreads();
    float sa = slot[0]+slot[1]+slot[2]+slot[3];
    float sb = slot[4]+slot[5]+slot[6]+slot[7];
    m = sa * (1.0f/256.0f);
    rs = rsqrtf(sb * (1.0f/256.0f) - m*m + 1e-5f);
  };

  // ---- params -> LDS ----
  for (int i = tid; i < 768; i += NTHR) {
    cals[i]  = CALW[i];
    obias[i] = p.sa_o_b[i];
    ff2b[i]  = p.ff2_b[i];
    ln1g[i] = p.ln1_g[i]; ln1b[i] = p.ln1_b[i];
    ln2g[i] = p.ln2_g[i]; ln2b[i] = p.ln2_b[i];
    ln3g[i] = p.ln3_g[i]; ln3b[i] = p.ln3_b[i];
  }
  for (int i = tid; i < 2304; i += NTHR) qkvb[i] = p.sa_qkv_b[i];
  for (int i = tid; i < 3072; i += NTHR) ff1b[i] = p.ff1_b[i];
  for (int i = tid; i < DDIM*NOUT; i += NTHR) embw[i] = p.emb_w[i];
  for (int i = tid; i < DDIM; i += NTHR) embb[i] = p.emb_b[i];
  for (int i = tid; i < 128; i += NTHR) opb1[i] = p.op_b1[i];
  for (int i = tid; i < NOUT*128; i += NTHR) opw2[i] = p.op_w2[i];
  if (tid < NOUT) OUTV[tid] = p.start_token[tid];
  if (tid < 8) opb2[tid] = (tid < NOUT) ? p.op_b2[tid] : 0.f;

  const float divv = (tid < 256) ? expf(-0.035977892078031968f * (float)(2*(tid>>1))) : 0.f;
  __syncthreads();

  // prologue: x(t=0)
  if (tid < 256) {
    float acc = embb[tid] + ((tid & 1) ? 1.0f : 0.0f);   // pe(t=0): sin0=0, cos0=1
    #pragma unroll
    for (int j = 0; j < NOUT; ++j) acc += OUTV[j] * embw[tid*NOUT + j];
    xls[tid] = acc;
  }
  __syncthreads();

  for (int t = 0; t < TSEQ; ++t) {
    for (int l = 0; l < NLAY; ++l) {
      // ---- build x for l>0: ln3(x2 + ff2out) ----
      if (l > 0) {
        float r2 = 0.f;
        if (tid < 256) r2 = x2ls[tid] + ffo[tid] + ff2b[(l-1)*256 + tid];
        float m, rs; lnstats(r2, lred + 0, m, rs);
        if (tid < 256)
          xls[tid] = (r2 - m) * rs * ln3g[(l-1)*256 + tid] + ln3b[(l-1)*256 + tid];
        __syncthreads();
      }
      // ---- qkv: 3 passes of 256 rows (Q, K, V), direct global weights ----
      #pragma unroll
      for (int ps = 0; ps < 3; ++ps) {
        int rowIdx = ps*256 + row4;
        const unsigned short* w = WQKV + ((size_t)(l*768 + rowIdx))*256 + kk*64;
        float acc = 0.f;
        #pragma unroll
        for (int i = 0; i < 8; ++i) {
          const uint4 u = *(const uint4*)(w + i*8);
          acc += dot8(u, xls, kk*64 + i*8);
        }
        acc += __shfl_xor(acc, 1);
        acc += __shfl_xor(acc, 2);
        if (kk == 0) {
          float v = acc + qkvb[l*768 + rowIdx];
          if (ps == 0)      qh[row4] = v;
          else if (ps == 1) kg[(size_t)(l*TSEQ + t)*256 + row4] = v;
          else              vg[(size_t)(l*TSEQ + t)*256 + row4] = v;
        }
      }
      __syncthreads();   // qh LDS + kg/vg global stores complete (vmcnt drained)
      // ---- scores + softmax: waves 0..7, head = wv ----
      if (wv < 8) {
        int j = ln;
        float scj = -1e30f;
        if (j <= t) {
          const float* kr = kg + (size_t)(l*TSEQ + j)*256 + wv*32;
          float a = 0.f;
          #pragma unroll
          for (int d0 = 0; d0 < 8; ++d0) {
            float4 kq = *(const float4*)(kr + d0*4);
            a += kq.x*qh[wv*32 + d0*4] + kq.y*qh[wv*32 + d0*4 + 1]
               + kq.z*qh[wv*32 + d0*4 + 2] + kq.w*qh[wv*32 + d0*4 + 3];
          }
          scj = a * 0.17677669529663687f;
        }
        float mx = scj;
        #pragma unroll
        for (int off = 32; off; off >>= 1) mx = fmaxf(mx, __shfl_xor(mx, off));
        float e = (j <= t) ? expf(scj - mx) : 0.f;
        float su = e;
        #pragma unroll
        for (int off = 32; off; off >>= 1) su += __shfl_xor(su, off);
        sc[wv*64 + j] = e / su;
      }
      __syncthreads();
      // ---- PV: all 1024 threads: (h, d, jg) ----
      {
        int h = tid >> 7, rr = tid & 127, d = rr >> 2, jg = rr & 3;
        float acc = 0.f;
        for (int j = jg; j <= t; j += 4)
          acc += sc[h*64 + j] * vg[(size_t)(l*TSEQ + j)*256 + h*32 + d];
        acc += __shfl_xor(acc, 1);
        acc += __shfl_xor(acc, 2);
        if (jg == 0) ah[h*32 + d] = acc;
      }
      __syncthreads();
      // ---- oproj: 256 rows K=256 ----
      {
        const unsigned short* w = WWO + ((size_t)(l*256 + row4))*256 + kk*64;
        float acc = 0.f;
        #pragma unroll
        for (int i = 0; i < 8; ++i) {
          const uint4 u = *(const uint4*)(w + i*8);
          acc += dot8(u, ah, kk*64 + i*8);
        }
        acc += __shfl_xor(acc, 1);
        acc += __shfl_xor(acc, 2);
        if (kk == 0) obuf[row4] = acc;
      }
      __syncthreads();
      // ---- residual + ln1 + ca + ln2 ----
      float r = 0.f;
      if (tid < 256) r = xls[tid] + obuf[tid] + obias[l*256 + tid];
      float m1, rs1; lnstats(r, lred + 8, m1, rs1);
      float z = 0.f;
      if (tid < 256)
        z = (r - m1)*rs1*ln1g[l*256 + tid] + ln1b[l*256 + tid] + cals[l*256 + tid];
      float m2, rs2; lnstats(z, lred + 16, m2, rs2);
      if (tid < 256) x2ls[tid] = (z - m2)*rs2*ln2g[l*256 + tid] + ln2b[l*256 + tid];
      __syncthreads();
      // ---- ff1: 4 passes of 256 rows ----
      #pragma unroll
      for (int ps = 0; ps < 4; ++ps) {
        int rowIdx = ps*256 + row4;
        const unsigned short* w = WF1 + ((size_t)(l*1024 + rowIdx))*256 + kk*64;
        float acc = 0.f;
        #pragma unroll
        for (int i = 0; i < 8; ++i) {
          const uint4 u = *(const uint4*)(w + i*8);
          acc += dot8(u, x2ls, kk*64 + i*8);
        }
        acc += __shfl_xor(acc, 1);
        acc += __shfl_xor(acc, 2);
        if (kk == 0) fxl[rowIdx] = gelu_exact(acc + ff1b[l*1024 + rowIdx]);
      }
      __syncthreads();
      // ---- ff2: 256 rows K=1024, kk-split 256 each ----
      {
        const unsigned short* w = WF2 + ((size_t)(l*256 + row4))*1024 + kk*256;
        float acc = 0.f;
        #pragma unroll
        for (int c = 0; c < 4; ++c) {
          #pragma unroll
          for (int i = 0; i < 8; ++i) {
            const uint4 u = *(const uint4*)(w + c*64 + i*8);
            acc += dot8(u, fxl, kk*256 + c*64 + i*8);
          }
        }
        acc += __shfl_xor(acc, 1);
        acc += __shfl_xor(acc, 2);
        if (kk == 0) ffo[row4] = acc;
      }
      __syncthreads();
    } // l

    // ---- step tail: ln3(l2) + output head + next x ----
    {
      float r2 = 0.f;
      if (tid < 256) r2 = x2ls[tid] + ffo[tid] + ff2b[2*256 + tid];
      float m, rs; lnstats(r2, lred + 24, m, rs);
      if (tid < 256) xls[tid] = (r2 - m)*rs*ln3g[2*256 + tid] + ln3b[2*256 + tid];
      __syncthreads();
      if (row4 < 128) {
        const unsigned short* w = WOP1 + (size_t)row4*256 + kk*64;
        float acc = 0.f;
        #pragma unroll
        for (int i = 0; i < 8; ++i) {
          const uint4 u = *(const uint4*)(w + i*8);
          acc += dot8(u, xls, kk*64 + i*8);
        }
        acc += __shfl_xor(acc, 1);
        acc += __shfl_xor(acc, 2);
        if (kk == 0) fxl[row4] = gelu_exact(acc + opb1[row4]);
      }
      __syncthreads();
      if (tid < 192) {
        int oo = tid >> 5, kl = tid & 31;
        float acc = fxl[kl]*opw2[oo*128 + kl] + fxl[kl+32]*opw2[oo*128 + kl+32]
                  + fxl[kl+64]*opw2[oo*128 + kl+64] + fxl[kl+96]*opw2[oo*128 + kl+96];
        #pragma unroll
        for (int off = 16; off; off >>= 1) acc += __shfl_xor(acc, off);
        if (kl == 0) {
          float v = acc + opb2[oo];
          OUTV[oo] = v;
          p.out[((size_t)g*TSEQ + t)*NOUT + oo] = v;
        }
      }
      __syncthreads();
      if (tid < 256) {
        float ang = (float)(t + 1) * divv;
        float pe = (tid & 1) ? cosf(ang) : sinf(ang);
        float acc = embb[tid] + pe;
        #pragma unroll
        for (int j = 0; j < NOUT; ++j) acc += OUTV[j] * embw[tid*NOUT + j];
        xls[tid] = acc;
      }
      __syncthreads();
    }
  } // t
}

extern "C" void kernel_launch(void* const* d_in, const int* in_sizes, int n_in,
                              void* d_out, int out_size, void* d_ws, size_t ws_size,
                              hipStream_t stream) {
  const float* const* F = (const float* const*)d_in;
  const float* z_style = F[0]; const float* z_skill = F[1];
  DecP p;
  p.start_token = F[2];
  const float* mem_w1 = F[3]; const float* mem_b1 = F[4];
  const float* mem_ln_g = F[5]; const float* mem_ln_b = F[6];
  const float* mem_w2 = F[7]; const float* mem_b2 = F[8];
  p.emb_w = F[9]; p.emb_b = F[10];
  const float* sa_qkv_w = F[11]; p.sa_qkv_b = F[12];
  const float* sa_o_w  = F[13]; p.sa_o_b = F[14];
  const float* ca_qkv_w = F[15]; const float* ca_qkv_b = F[16];
  const float* ca_o_w = F[17]; const float* ca_o_b = F[18];
  p.ln1_g = F[19]; p.ln1_b = F[20]; p.ln2_g = F[21]; p.ln2_b = F[22];
  p.ln3_g = F[23]; p.ln3_b = F[24];
  const float* ff1_w = F[25]; p.ff1_b = F[26];
  const float* ff2_w = F[27]; p.ff2_b = F[28];
  const float* op_w1 = F[29]; p.op_b1 = F[30]; p.op_w2 = F[31]; p.op_b2 = F[32];
  p.out = (float*)d_out;
  p.ws  = (unsigned char*)d_ws;

  convert_bf16<<<dim3(512), dim3(256), 0, stream>>>(sa_qkv_w, sa_o_w, ff1_w, ff2_w, op_w1,
                                                    (unsigned char*)d_ws);
  precompute_ca<<<dim3(48), dim3(256), 0, stream>>>(z_style, z_skill, mem_w1, mem_b1,
                                                    mem_ln_g, mem_ln_b, mem_w2, mem_b2,
                                                    ca_qkv_w, ca_qkv_b, ca_o_w, ca_o_b,
                                                    (unsigned char*)d_ws);
  decoder_persistent<<<dim3(NGRP), dim3(NTHR), 0, stream>>>(p);
}

// Round 13
// 2721.940 us; speedup vs baseline: 2.9435x; 2.9435x over previous
//
#include <hip/hip_runtime.h>
#include <hip/hip_bf16.h>
#include <math.h>

// ---------------- problem constants ----------------
#define NGRP2 8     // groups of 8 WGs; each group handles TWO batch elements
#define GWG  8
#define NBLK (NGRP2*GWG)   // 64; group g's blocks all ≡ g (mod 8) -> same XCD
#define NTHR 512
#define TSEQ 48
#define DDIM 256
#define HDIM 32
#define NLAY 3
#define NOUT 6

// ---------------- ws layout ----------------
#define CNT_OFF   0u
#define CNT_BYTES 8192u          // 8 groups x 8 flag slots x 128B
#define GRP_OFF   16384u         // per-ELEMENT precompute region (stride 5120 floats)
#define GRP_STRF  5120u
#define CAL_F  4096              // [3*256] cross-attn constants (per element)
#define WB_OFF 360448u           // bf16 weights (element offsets below)
#define WOFF_QKV 0u
#define WOFF_WO  589824u
#define WOFF_F1  786432u
#define WOFF_F2  1572864u
#define WOFF_OP1 2359296u
#define NCVT     2392064u
#define EXCH_OFF 5505024u        // per-group exchange: 8192 floats (Po[2][8][256], Pf[2][8][256])

typedef __attribute__((address_space(1))) const unsigned int gu32;
typedef __attribute__((address_space(3))) unsigned int lu32;

__device__ __forceinline__ void gl_lds16(const unsigned short* g, unsigned short* l) {
  __builtin_amdgcn_global_load_lds((gu32*)g, (lu32*)l, 16, 0, 0);
}
__device__ __forceinline__ void bfp(unsigned int u, float& lo, float& hi) {
  union { unsigned int i; float f; } a, b;
  a.i = u << 16; b.i = u & 0xffff0000u; lo = a.f; hi = b.f;
}
__device__ __forceinline__ float bf2f(unsigned short u) {
  union { unsigned int i; float f; } c; c.i = ((unsigned int)u) << 16; return c.f;
}
__device__ __forceinline__ unsigned short f2bf(float f) {
  __hip_bfloat16 h = __float2bfloat16(f);
  union { __hip_bfloat16 h; unsigned short u; } c; c.h = h; return c.u;
}
__device__ __forceinline__ float gelu_exact(float x) {
  return 0.5f * x * (1.0f + erff(x * 0.70710678118654752f));
}
__device__ __forceinline__ float dot8(const uint4& u, const float* x, int k0) {
  float lo, hi, acc = 0.f;
  bfp(u.x, lo, hi); acc += x[k0  ]*lo + x[k0+1]*hi;
  bfp(u.y, lo, hi); acc += x[k0+2]*lo + x[k0+3]*hi;
  bfp(u.z, lo, hi); acc += x[k0+4]*lo + x[k0+5]*hi;
  bfp(u.w, lo, hi); acc += x[k0+6]*lo + x[k0+7]*hi;
  return acc;
}

// ---------------- weight fp32 -> bf16 ----------------
__global__ void convert_bf16(const float* qkv, const float* ow, const float* f1,
                             const float* f2, const float* w1, unsigned char* ws) {
  __hip_bfloat16* dst = (__hip_bfloat16*)(ws + WB_OFF);
  size_t stride = (size_t)gridDim.x * blockDim.x;
  for (size_t i = (size_t)blockIdx.x * blockDim.x + threadIdx.x; i < NCVT; i += stride) {
    float v;
    if      (i < WOFF_WO)  v = qkv[i];
    else if (i < WOFF_F1)  v = ow[i - WOFF_WO];
    else if (i < WOFF_F2)  v = f1[i - WOFF_F1];
    else if (i < WOFF_OP1) v = f2[i - WOFF_F2];
    else                   v = w1[i - WOFF_OP1];
    dst[i] = __float2bfloat16(v);
  }
}

// ---------------- one-shot per-(element,l): memvec chain + cross-attn const ----------------
__global__ void precompute_ca(const float* zs, const float* zk,
                              const float* mw1, const float* mb1,
                              const float* mlg, const float* mlb,
                              const float* mw2, const float* mb2,
                              const float* cqw, const float* cqb,
                              const float* cow, const float* cob,
                              unsigned char* ws) {
  const int g = blockIdx.x & 15, l = blockIdx.x >> 4;
  const int tid = threadIdx.x;           // 256 threads
  __shared__ float cond[128], h[256], mvv[256], vv[256], lred[16];

  auto lnstat = [&](float v, float& m, float& rs) {
    float a = v, b = v * v;
    #pragma unroll
    for (int off = 32; off; off >>= 1) { a += __shfl_xor(a, off); b += __shfl_xor(b, off); }
    if ((tid & 63) == 0) { lred[tid >> 6] = a; lred[4 + (tid >> 6)] = b; }
    __syncthreads();
    float sa = lred[0]+lred[1]+lred[2]+lred[3];
    float sb = lred[4]+lred[5]+lred[6]+lred[7];
    m = sa * (1.0f/256.0f);
    rs = rsqrtf(sb * (1.0f/256.0f) - m*m + 1e-5f);
    __syncthreads();
  };

  if (tid < 128) cond[tid] = (tid < 64) ? zs[g*64 + tid] : zk[g*64 + tid - 64];
  __syncthreads();
  float acc = mb1[tid];
  { const float* w = mw1 + (size_t)tid * 128;
    for (int k = 0; k < 128; k += 4) {
      float4 q = *(const float4*)(w + k);
      acc += q.x*cond[k] + q.y*cond[k+1] + q.z*cond[k+2] + q.w*cond[k+3];
    } }
  float m, rs; lnstat(acc, m, rs);
  h[tid] = gelu_exact((acc - m) * rs * mlg[tid] + mlb[tid]);
  __syncthreads();
  float a2 = mb2[tid];
  { const float* w = mw2 + (size_t)tid * 256;
    for (int k = 0; k < 256; k += 4) {
      float4 q = *(const float4*)(w + k);
      a2 += q.x*h[k] + q.y*h[k+1] + q.z*h[k+2] + q.w*h[k+3];
    } }
  mvv[tid] = a2;
  __syncthreads();
  float a3 = cqb[l*768 + 512 + tid];
  { const float* w = cqw + ((size_t)l*768 + 512 + tid) * 256;
    for (int k = 0; k < 256; k += 4) {
      float4 q = *(const float4*)(w + k);
      a3 += q.x*mvv[k] + q.y*mvv[k+1] + q.z*mvv[k+2] + q.w*mvv[k+3];
    } }
  vv[tid] = a3;
  __syncthreads();
  float a4 = cob[l*256 + tid];
  { const float* w = cow + ((size_t)l*256 + tid) * 256;
    for (int k = 0; k < 256; k += 4) {
      float4 q = *(const float4*)(w + k);
      a4 += q.x*vv[k] + q.y*vv[k+1] + q.z*vv[k+2] + q.w*vv[k+3];
    } }
  ((float*)(ws + GRP_OFF))[(size_t)g * GRP_STRF + CAL_F + l*256 + tid] = a4;
}

struct DecP {
  const float *start_token, *emb_w, *emb_b;
  const float *sa_qkv_b, *sa_o_b;
  const float *ln1_g, *ln1_b, *ln2_g, *ln2_b, *ln3_g, *ln3_b;
  const float *ff1_b, *ff2_b;
  const float *op_b1, *op_w2, *op_b2;
  float* out;
  unsigned char* ws;
};

// Persistent dual-element decoder: 8 groups x 8 WGs x 512 threads, each group
// handles 2 batch elements. R10 structure/mappings; GEMVs are dual-accumulator
// (one weight load -> two elements), per-el ops split by el = tid>>8.
__global__ __launch_bounds__(NTHR, 1) void decoder_persistent(DecP p) {
  const int gg = blockIdx.x & 7;       // group id (= XCD under round-robin)
  const int s = blockIdx.x >> 3;       // head / slice id 0..7
  const int tid = threadIdx.x;

  unsigned int* flg = (unsigned int*)(p.ws + CNT_OFF) + (size_t)gg * 256;  // 8 slots x 128B
  float* EX = (float*)(p.ws + EXCH_OFF) + (size_t)gg * 8192;
  float* PoG = EX;            // [el][8][256]
  float* PfG = EX + 4096;     // [el][8][256]
  const float* GRPW = (const float*)(p.ws + GRP_OFF);
  const unsigned short* WB = (const unsigned short*)(p.ws + WB_OFF);

  __shared__ __align__(16) unsigned short Rws[32768];        // 64KB weight stage
  __shared__ __align__(16) unsigned short kcb[2][NLAY*TSEQ*34];  // bf16 K cache, pad 34
  __shared__ __align__(16) unsigned short vcb[2][NLAY*TSEQ*34];  // bf16 V cache
  __shared__ float xls[2][DDIM], x2ls[2][DDIM], lred[64], fxl[2][128];
  __shared__ float qb[2][HDIM], ah[2][HDIM], sc[2][64];
  __shared__ float cals[2*768], obias[768], ff2b[768];
  __shared__ float ln1g[768], ln1b[768], ln2g[768], ln2b[768], ln3g[768], ln3b[768];
  __shared__ float qkvb[288], ff1b[384];
  __shared__ float embw[DDIM*NOUT], embb[DDIM];
  __shared__ float opb1[128], opw2[NOUT*128], opb2[8], OUTV[2][8];

  const int row = tid >> 2, kk = tid & 3;    // 4 threads per GEMV output row
  const int el = tid >> 8, tl = tid & 255;   // element split for per-el ops
  const int wv = tid >> 6, ln = tid & 63;    // wave id / lane id

  // ---- weight staging (R10-proven; weights shared by both elements) ----
  auto stage_qkv = [&](int l) {
    #pragma unroll
    for (int r = 0; r < 6; ++r) {
      int c = (r*8 + wv)*64 + ln;
      int rw = c >> 5, wc = (c & 31) ^ (rw & 7);
      const unsigned short* gp = WB + WOFF_QKV
        + ((size_t)(l*768 + (rw>>5)*256 + s*32 + (rw&31)))*256 + wc*8;
      gl_lds16(gp, Rws + (size_t)(r*8 + wv)*512);
    }
  };
  auto stage_ff1 = [&](int l) {
    #pragma unroll
    for (int r = 0; r < 8; ++r) {
      int c = (r*8 + wv)*64 + ln;
      int rw = c >> 5, wc = (c & 31) ^ (rw & 7);
      const unsigned short* gp = WB + WOFF_F1
        + ((size_t)(l*1024 + s*128 + rw))*256 + wc*8;
      gl_lds16(gp, Rws + (size_t)(r*8 + wv)*512);
    }
  };
  auto stage_ff2 = [&](int l) {
    #pragma unroll
    for (int r = 0; r < 8; ++r) {
      int c = (r*8 + wv)*64 + ln;
      int rw = c >> 4, wc = (c & 15) ^ (rw & 15);
      const unsigned short* gp = WB + WOFF_F2
        + ((size_t)(l*256 + rw))*1024 + s*128 + wc*8;
      gl_lds16(gp, Rws + (size_t)(r*8 + wv)*512);
    }
  };

  // ---- register weight tiles (same rows for both halves) ----
  uint4 pWO[4], pO1[8];
  auto ldWO = [&](int l) {         // o-proj row tl, full own-head k-slice
    const unsigned short* w = WB + WOFF_WO + ((size_t)(l*256 + tl))*256 + s*32;
    #pragma unroll
    for (int c = 0; c < 4; ++c) pWO[c] = *(const uint4*)(w + c*8);
  };
  auto ldO1 = [&]() {              // op_w1 rows (row<128, kk quarter)
    const unsigned short* w = WB + WOFF_OP1 + (size_t)row*256 + kk*64;
    #pragma unroll
    for (int i = 0; i < 8; ++i) pO1[i] = *(const uint4*)(w + i*8);
  };

  // ---- flag-vector barrier (R6-proven) ----
  unsigned int barcount = 0;
  auto gbar = [&]() {
    __syncthreads();
    ++barcount;
    if (tid == 0)
      __hip_atomic_store(flg + s*32, barcount, __ATOMIC_RELEASE, __HIP_MEMORY_SCOPE_AGENT);
    if (tid < GWG) {
      while (__hip_atomic_load(flg + tid*32, __ATOMIC_RELAXED, __HIP_MEMORY_SCOPE_AGENT) < barcount) {}
    }
    if (tid == 0)
      (void)__hip_atomic_load(flg + s*32, __ATOMIC_ACQUIRE, __HIP_MEMORY_SCOPE_AGENT);
    __syncthreads();
  };

  // ---- single-sync dual-element LN stats (waves 0-3 el0, 4-7 el1) ----
  auto lnstats = [&](float v, float* slot, float& m, float& rs) {
    float a = v, b = v * v;
    #pragma unroll
    for (int off = 32; off; off >>= 1) { a += __shfl_xor(a, off); b += __shfl_xor(b, off); }
    if (ln == 0) { slot[wv] = a; slot[8 + wv] = b; }
    __syncthreads();
    int b0 = el*4;
    float sa = slot[b0]+slot[b0+1]+slot[b0+2]+slot[b0+3];
    float sb = slot[8+b0]+slot[9+b0]+slot[10+b0]+slot[11+b0];
    m = sa * (1.0f/256.0f);
    rs = rsqrtf(sb * (1.0f/256.0f) - m*m + 1e-5f);
  };

  // ---- params -> LDS ----
  for (int i = tid; i < 768; i += NTHR) {
    obias[i] = p.sa_o_b[i];
    ff2b[i]  = p.ff2_b[i];
    ln1g[i] = p.ln1_g[i]; ln1b[i] = p.ln1_b[i];
    ln2g[i] = p.ln2_g[i]; ln2b[i] = p.ln2_b[i];
    ln3g[i] = p.ln3_g[i]; ln3b[i] = p.ln3_b[i];
  }
  for (int i = tid; i < 2*768; i += NTHR) {
    int eh = i / 768;
    cals[i] = GRPW[(size_t)(gg*2 + eh) * GRP_STRF + CAL_F + (i % 768)];
  }
  for (int i = tid; i < 288; i += NTHR) {
    int l = i / 96, r = i % 96, sect = (r >> 5), o = r & 31;
    qkvb[i] = p.sa_qkv_b[l*768 + sect*256 + s*32 + o];
  }
  for (int i = tid; i < 384; i += NTHR) {
    int l = i >> 7, o = i & 127;
    ff1b[i] = p.ff1_b[l*1024 + s*128 + o];
  }
  for (int i = tid; i < DDIM*NOUT; i += NTHR) embw[i] = p.emb_w[i];
  for (int i = tid; i < DDIM; i += NTHR) embb[i] = p.emb_b[i];
  for (int i = tid; i < 128; i += NTHR) opb1[i] = p.op_b1[i];
  for (int i = tid; i < NOUT*128; i += NTHR) opw2[i] = p.op_w2[i];
  if (tl < NOUT) OUTV[el][tl] = p.start_token[tl];
  if (tid < 8) opb2[tid] = (tid < NOUT) ? p.op_b2[tid] : 0.f;

  const float divv = expf(-0.035977892078031968f * (float)(2*(tl>>1)));
  __syncthreads();

  // prologue: x(t=0) both elements + stage qkv(0) + WO(0)
  {
    float acc = embb[tl] + ((tl & 1) ? 1.0f : 0.0f);
    #pragma unroll
    for (int j = 0; j < NOUT; ++j) acc += OUTV[el][j] * embw[tl*NOUT + j];
    xls[el][tl] = acc;
  }
  stage_qkv(0);
  ldWO(0);
  __syncthreads();

  for (int t = 0; t < TSEQ; ++t) {
    for (int l = 0; l < NLAY; ++l) {
      // ================= PHASE Q =================
      if (l > 0) {
        float r2 = x2ls[el][tl] + ff2b[(l-1)*256 + tl];
        #pragma unroll
        for (int ss = 0; ss < GWG; ++ss) r2 += PfG[el*2048 + ss*256 + tl];
        float m, rs; lnstats(r2, lred + 0, m, rs);
        xls[el][tl] = (r2 - m) * rs * ln3g[(l-1)*256 + tl] + ln3b[(l-1)*256 + tl];
        __syncthreads();
      }
      // qkv: dual-accumulator GEMV (one weight load, two elements)
      if (row < 96) {
        float aA = 0.f, aB = 0.f;
        #pragma unroll
        for (int i = 0; i < 8; ++i) {
          int ii = (i + kk) & 7;
          int k0 = kk*64 + ii*8;
          const uint4 w = *(const uint4*)(Rws + row*256 + (k0 ^ ((row&7)<<3)));
          aA += dot8(w, xls[0], k0);
          aB += dot8(w, xls[1], k0);
        }
        aA += __shfl_xor(aA, 1); aA += __shfl_xor(aA, 2);
        aB += __shfl_xor(aB, 1); aB += __shfl_xor(aB, 2);
        if (kk == 0) {
          float bq = qkvb[l*96 + row];
          float vA = aA + bq, vB = aB + bq;
          int sect = row >> 5, o = row & 31;
          if (sect == 0) { qb[0][o] = vA; qb[1][o] = vB; }
          else if (sect == 1) {
            kcb[0][(l*TSEQ + t)*34 + o] = f2bf(vA);
            kcb[1][(l*TSEQ + t)*34 + o] = f2bf(vB);
          } else {
            vcb[0][(l*TSEQ + t)*34 + o] = f2bf(vA);
            vcb[1][(l*TSEQ + t)*34 + o] = f2bf(vB);
          }
        }
      }
      __syncthreads();
      stage_ff1(l);              // async; drains by a later sync
      // scores + softmax: wave 0 -> element 0, wave 1 -> element 1
      if (wv < 2) {
        int ee = wv, j = ln;
        float scj = -1e30f;
        if (j <= t) {
          const unsigned short* kr = &kcb[ee][(l*TSEQ + j)*34];
          float a = 0.f;
          #pragma unroll
          for (int c = 0; c < 16; ++c) {
            unsigned int u = *(const unsigned int*)(kr + c*2);
            float lo, hi; bfp(u, lo, hi);
            a += lo*qb[ee][2*c] + hi*qb[ee][2*c + 1];
          }
          scj = a * 0.17677669529663687f;
        }
        float mx = scj;
        #pragma unroll
        for (int off = 32; off; off >>= 1) mx = fmaxf(mx, __shfl_xor(mx, off));
        float e = (j <= t) ? expf(scj - mx) : 0.f;
        float su = e;
        #pragma unroll
        for (int off = 32; off; off >>= 1) su += __shfl_xor(su, off);
        sc[ee][j] = e / su;
      }
      __syncthreads();
      // PV: per-element halves, 8 lanes per d
      {
        int d = tl >> 3, jg = tl & 7;
        float acc = 0.f;
        for (int j = jg; j <= t; j += 8)
          acc += sc[el][j] * bf2f(vcb[el][(l*TSEQ + j)*34 + d]);
        acc += __shfl_xor(acc, 1);
        acc += __shfl_xor(acc, 2);
        acc += __shfl_xor(acc, 4);
        if (jg == 0) ah[el][d] = acc;
      }
      __syncthreads();
      // oproj: full own-head dot per thread (row tl, element el)
      {
        float acc = 0.f;
        #pragma unroll
        for (int c = 0; c < 4; ++c) acc += dot8(pWO[c], ah[el], c*8);
        PoG[el*2048 + s*256 + tl] = acc;
      }
      gbar();   // B1

      // ================= PHASE F =================
      float r = xls[el][tl] + obias[l*256 + tl];
      #pragma unroll
      for (int ss = 0; ss < GWG; ++ss) r += PoG[el*2048 + ss*256 + tl];
      float m1, rs1; lnstats(r, lred + 16, m1, rs1);
      float z = (r - m1)*rs1*ln1g[l*256 + tl] + ln1b[l*256 + tl] + cals[el*768 + l*256 + tl];
      float m2, rs2; lnstats(z, lred + 32, m2, rs2);
      x2ls[el][tl] = (z - m2)*rs2*ln2g[l*256 + tl] + ln2b[l*256 + tl];
      __syncthreads();
      // ff1: dual-accumulator GEMV (128 rows, 4 lanes/row)
      {
        float aA = 0.f, aB = 0.f;
        #pragma unroll
        for (int i = 0; i < 8; ++i) {
          int ii = (i + kk) & 7;
          int k0 = kk*64 + ii*8;
          const uint4 w = *(const uint4*)(Rws + row*256 + (k0 ^ ((row&7)<<3)));
          aA += dot8(w, x2ls[0], k0);
          aB += dot8(w, x2ls[1], k0);
        }
        aA += __shfl_xor(aA, 1); aA += __shfl_xor(aA, 2);
        aB += __shfl_xor(aB, 1); aB += __shfl_xor(aB, 2);
        __syncthreads();           // all ff1 Rws reads done
        stage_ff2(l);              // async
        if (kk == 0) {
          float bf = ff1b[l*128 + row];
          fxl[0][row] = gelu_exact(aA + bf);
          fxl[1][row] = gelu_exact(aB + bf);
        }
      }
      __syncthreads();             // drains ff2 DMA + fxl visible
      // ff2: full own-k-slice dot per thread (row tl, element el)
      {
        float acc2 = 0.f;
        #pragma unroll
        for (int j2 = 0; j2 < 16; ++j2) {
          int k0 = j2*8;
          const uint4 w = *(const uint4*)(Rws + tl*128 + (k0 ^ ((tl&15)<<3)));
          acc2 += dot8(w, fxl[el], k0);
        }
        PfG[el*2048 + s*256 + tl] = acc2;
      }
      __syncthreads();             // ff2 Rws reads done
      {
        int lnx = (l == 2) ? 0 : l + 1;
        stage_qkv(lnx);            // async; drains across B2
        ldWO(lnx);
        if (l == 2) ldO1();
      }
      gbar();   // B2
    } // l

    // ============ STEP TAIL: ln3(l2) + output head + next-step x ========
    {
      float r2 = x2ls[el][tl] + ff2b[2*256 + tl];
      #pragma unroll
      for (int ss = 0; ss < GWG; ++ss) r2 += PfG[el*2048 + ss*256 + tl];
      float m, rs; lnstats(r2, lred + 48, m, rs);
      xls[el][tl] = (r2 - m)*rs*ln3g[2*256 + tl] + ln3b[2*256 + tl];
      __syncthreads();
      // op1: dual-accumulator from register tile
      {
        float aA = 0.f, aB = 0.f;
        #pragma unroll
        for (int i = 0; i < 8; ++i) {
          aA += dot8(pO1[i], xls[0], kk*64 + i*8);
          aB += dot8(pO1[i], xls[1], kk*64 + i*8);
        }
        aA += __shfl_xor(aA, 1); aA += __shfl_xor(aA, 2);
        aB += __shfl_xor(aB, 1); aB += __shfl_xor(aB, 2);
        if (kk == 0) {
          float bo = opb1[row];
          fxl[0][row] = gelu_exact(aA + bo);
          fxl[1][row] = gelu_exact(aB + bo);
        }
      }
      __syncthreads();
      // op2 per element
      if (tl < 192) {
        int oo = tl >> 5, kl = tl & 31;
        float acc = fxl[el][kl]*opw2[oo*128 + kl] + fxl[el][kl+32]*opw2[oo*128 + kl+32]
                  + fxl[el][kl+64]*opw2[oo*128 + kl+64] + fxl[el][kl+96]*opw2[oo*128 + kl+96];
        #pragma unroll
        for (int off = 16; off; off >>= 1) acc += __shfl_xor(acc, off);
        if (kl == 0) {
          float v = acc + opb2[oo];
          OUTV[el][oo] = v;
          if (s == 0) p.out[((size_t)(gg*2 + el)*TSEQ + t)*NOUT + oo] = v;
        }
      }
      __syncthreads();
      // next-step x build (both elements; harmless at t=47)
      {
        float ang = (float)(t + 1) * divv;
        float pe = (tl & 1) ? cosf(ang) : sinf(ang);
        float acc = embb[tl] + pe;
        #pragma unroll
        for (int j = 0; j < NOUT; ++j) acc += OUTV[el][j] * embw[tl*NOUT + j];
        xls[el][tl] = acc;
      }
      __syncthreads();
    }
  } // t
}

extern "C" void kernel_launch(void* const* d_in, const int* in_sizes, int n_in,
                              void* d_out, int out_size, void* d_ws, size_t ws_size,
                              hipStream_t stream) {
  const float* const* F = (const float* const*)d_in;
  const float* z_style = F[0]; const float* z_skill = F[1];
  DecP p;
  p.start_token = F[2];
  const float* mem_w1 = F[3]; const float* mem_b1 = F[4];
  const float* mem_ln_g = F[5]; const float* mem_ln_b = F[6];
  const float* mem_w2 = F[7]; const float* mem_b2 = F[8];
  p.emb_w = F[9]; p.emb_b = F[10];
  const float* sa_qkv_w = F[11]; p.sa_qkv_b = F[12];
  const float* sa_o_w  = F[13]; p.sa_o_b = F[14];
  const float* ca_qkv_w = F[15]; const float* ca_qkv_b = F[16];
  const float* ca_o_w = F[17]; const float* ca_o_b = F[18];
  p.ln1_g = F[19]; p.ln1_b = F[20]; p.ln2_g = F[21]; p.ln2_b = F[22];
  p.ln3_g = F[23]; p.ln3_b = F[24];
  const float* ff1_w = F[25]; p.ff1_b = F[26];
  const float* ff2_w = F[27]; p.ff2_b = F[28];
  const float* op_w1 = F[29]; p.op_b1 = F[30]; p.op_w2 = F[31]; p.op_b2 = F[32];
  p.out = (float*)d_out;
  p.ws  = (unsigned char*)d_ws;

  hipMemsetAsync((char*)d_ws + CNT_OFF, 0, CNT_BYTES, stream);
  convert_bf16<<<dim3(512), dim3(256), 0, stream>>>(sa_qkv_w, sa_o_w, ff1_w, ff2_w, op_w1,
                                                    (unsigned char*)d_ws);
  precompute_ca<<<dim3(48), dim3(256), 0, stream>>>(z_style, z_skill, mem_w1, mem_b1,
                                                    mem_ln_g, mem_ln_b, mem_w2, mem_b2,
                                                    ca_qkv_w, ca_qkv_b, ca_o_w, ca_o_b,
                                                    (unsigned char*)d_ws);
  decoder_persistent<<<dim3(NBLK), dim3(NTHR), 0, stream>>>(p);
}

// Round 14
// 2695.822 us; speedup vs baseline: 2.9720x; 1.0097x over previous
//
#include <hip/hip_runtime.h>
#include <hip/hip_bf16.h>
#include <math.h>

// ---------------- problem constants ----------------
#define NGRP2 8     // groups of 8 WGs; each group handles TWO batch elements
#define GWG  8
#define NBLK (NGRP2*GWG)   // 64; group g's blocks all ≡ g (mod 8) -> same XCD
#define NTHR 512
#define TSEQ 48
#define DDIM 256
#define HDIM 32
#define NLAY 3
#define NOUT 6

// ---------------- ws layout ----------------
#define CNT_OFF   0u
#define CNT_BYTES 8192u          // 8 groups x 8 flag slots x 128B
#define GRP_OFF   16384u         // per-ELEMENT precompute region (stride 5120 floats)
#define GRP_STRF  5120u
#define CAL_F  4096              // [3*256] cross-attn constants (per element)
#define WB_OFF 360448u           // bf16 weights (element offsets below)
#define WOFF_QKV 0u
#define WOFF_WO  589824u
#define WOFF_F1  786432u
#define WOFF_F2  1572864u
#define WOFF_OP1 2359296u
#define NCVT     2392064u
#define EXCH_OFF 5505024u        // per-group exchange: 8192 floats (Po[2][8][256], Pf[2][8][256])

typedef __attribute__((address_space(1))) const unsigned int gu32;
typedef __attribute__((address_space(3))) unsigned int lu32;

__device__ __forceinline__ void gl_lds16(const unsigned short* g, unsigned short* l) {
  __builtin_amdgcn_global_load_lds((gu32*)g, (lu32*)l, 16, 0, 0);
}
__device__ __forceinline__ void bfp(unsigned int u, float& lo, float& hi) {
  union { unsigned int i; float f; } a, b;
  a.i = u << 16; b.i = u & 0xffff0000u; lo = a.f; hi = b.f;
}
__device__ __forceinline__ float bf2f(unsigned short u) {
  union { unsigned int i; float f; } c; c.i = ((unsigned int)u) << 16; return c.f;
}
__device__ __forceinline__ unsigned short f2bf(float f) {
  __hip_bfloat16 h = __float2bfloat16(f);
  union { __hip_bfloat16 h; unsigned short u; } c; c.h = h; return c.u;
}
__device__ __forceinline__ float gelu_exact(float x) {
  return 0.5f * x * (1.0f + erff(x * 0.70710678118654752f));
}
__device__ __forceinline__ float dot8(const uint4& u, const float* x, int k0) {
  float lo, hi, acc = 0.f;
  bfp(u.x, lo, hi); acc += x[k0  ]*lo + x[k0+1]*hi;
  bfp(u.y, lo, hi); acc += x[k0+2]*lo + x[k0+3]*hi;
  bfp(u.z, lo, hi); acc += x[k0+4]*lo + x[k0+5]*hi;
  bfp(u.w, lo, hi); acc += x[k0+6]*lo + x[k0+7]*hi;
  return acc;
}

// ---------------- weight fp32 -> bf16 ----------------
__global__ void convert_bf16(const float* qkv, const float* ow, const float* f1,
                             const float* f2, const float* w1, unsigned char* ws) {
  __hip_bfloat16* dst = (__hip_bfloat16*)(ws + WB_OFF);
  size_t stride = (size_t)gridDim.x * blockDim.x;
  for (size_t i = (size_t)blockIdx.x * blockDim.x + threadIdx.x; i < NCVT; i += stride) {
    float v;
    if      (i < WOFF_WO)  v = qkv[i];
    else if (i < WOFF_F1)  v = ow[i - WOFF_WO];
    else if (i < WOFF_F2)  v = f1[i - WOFF_F1];
    else if (i < WOFF_OP1) v = f2[i - WOFF_F2];
    else                   v = w1[i - WOFF_OP1];
    dst[i] = __float2bfloat16(v);
  }
}

// ---------------- one-shot per-(element,l): memvec chain + cross-attn const ----------------
__global__ void precompute_ca(const float* zs, const float* zk,
                              const float* mw1, const float* mb1,
                              const float* mlg, const float* mlb,
                              const float* mw2, const float* mb2,
                              const float* cqw, const float* cqb,
                              const float* cow, const float* cob,
                              unsigned char* ws) {
  const int g = blockIdx.x & 15, l = blockIdx.x >> 4;
  const int tid = threadIdx.x;           // 256 threads
  __shared__ float cond[128], h[256], mvv[256], vv[256], lred[16];

  auto lnstat = [&](float v, float& m, float& rs) {
    float a = v, b = v * v;
    #pragma unroll
    for (int off = 32; off; off >>= 1) { a += __shfl_xor(a, off); b += __shfl_xor(b, off); }
    if ((tid & 63) == 0) { lred[tid >> 6] = a; lred[4 + (tid >> 6)] = b; }
    __syncthreads();
    float sa = lred[0]+lred[1]+lred[2]+lred[3];
    float sb = lred[4]+lred[5]+lred[6]+lred[7];
    m = sa * (1.0f/256.0f);
    rs = rsqrtf(sb * (1.0f/256.0f) - m*m + 1e-5f);
    __syncthreads();
  };

  if (tid < 128) cond[tid] = (tid < 64) ? zs[g*64 + tid] : zk[g*64 + tid - 64];
  __syncthreads();
  float acc = mb1[tid];
  { const float* w = mw1 + (size_t)tid * 128;
    for (int k = 0; k < 128; k += 4) {
      float4 q = *(const float4*)(w + k);
      acc += q.x*cond[k] + q.y*cond[k+1] + q.z*cond[k+2] + q.w*cond[k+3];
    } }
  float m, rs; lnstat(acc, m, rs);
  h[tid] = gelu_exact((acc - m) * rs * mlg[tid] + mlb[tid]);
  __syncthreads();
  float a2 = mb2[tid];
  { const float* w = mw2 + (size_t)tid * 256;
    for (int k = 0; k < 256; k += 4) {
      float4 q = *(const float4*)(w + k);
      a2 += q.x*h[k] + q.y*h[k+1] + q.z*h[k+2] + q.w*h[k+3];
    } }
  mvv[tid] = a2;
  __syncthreads();
  float a3 = cqb[l*768 + 512 + tid];
  { const float* w = cqw + ((size_t)l*768 + 512 + tid) * 256;
    for (int k = 0; k < 256; k += 4) {
      float4 q = *(const float4*)(w + k);
      a3 += q.x*mvv[k] + q.y*mvv[k+1] + q.z*mvv[k+2] + q.w*mvv[k+3];
    } }
  vv[tid] = a3;
  __syncthreads();
  float a4 = cob[l*256 + tid];
  { const float* w = cow + ((size_t)l*256 + tid) * 256;
    for (int k = 0; k < 256; k += 4) {
      float4 q = *(const float4*)(w + k);
      a4 += q.x*vv[k] + q.y*vv[k+1] + q.z*vv[k+2] + q.w*vv[k+3];
    } }
  ((float*)(ws + GRP_OFF))[(size_t)g * GRP_STRF + CAL_F + l*256 + tid] = a4;
}

struct DecP {
  const float *start_token, *emb_w, *emb_b;
  const float *sa_qkv_b, *sa_o_b;
  const float *ln1_g, *ln1_b, *ln2_g, *ln2_b, *ln3_g, *ln3_b;
  const float *ff1_b, *ff2_b;
  const float *op_b1, *op_w2, *op_b2;
  float* out;
  unsigned char* ws;
};

// Persistent dual-element decoder: 8 groups x 8 WGs x 512 threads, each group
// handles 2 batch elements. R10 structure/mappings; GEMVs are dual-accumulator
// (one weight load -> two elements), per-el ops split by el = tid>>8.
__global__ __launch_bounds__(NTHR, 1) void decoder_persistent(DecP p) {
  const int gg = blockIdx.x & 7;       // group id (= XCD under round-robin)
  const int s = blockIdx.x >> 3;       // head / slice id 0..7
  const int tid = threadIdx.x;

  unsigned int* flg = (unsigned int*)(p.ws + CNT_OFF) + (size_t)gg * 256;  // 8 slots x 128B
  float* EX = (float*)(p.ws + EXCH_OFF) + (size_t)gg * 8192;
  float* PoG = EX;            // [el][8][256]
  float* PfG = EX + 4096;     // [el][8][256]
  const float* GRPW = (const float*)(p.ws + GRP_OFF);
  const unsigned short* WB = (const unsigned short*)(p.ws + WB_OFF);

  __shared__ __align__(16) unsigned short Rws[32768];        // 64KB weight stage
  __shared__ __align__(16) unsigned short kcb[2][NLAY*TSEQ*34];  // bf16 K cache, pad 34
  __shared__ __align__(16) unsigned short vcb[2][NLAY*TSEQ*34];  // bf16 V cache
  __shared__ float xls[2][DDIM], x2ls[2][DDIM], lred[64], fxl[2][128];
  __shared__ float qb[2][HDIM], ah[2][HDIM], sc[2][64];
  __shared__ float cals[2*768], obias[768], ff2b[768];
  __shared__ float ln1g[768], ln1b[768], ln2g[768], ln2b[768], ln3g[768], ln3b[768];
  __shared__ float qkvb[288], ff1b[384];
  __shared__ float embw[DDIM*NOUT], embb[DDIM];
  __shared__ float opb1[128], opw2[NOUT*128], opb2[8], OUTV[2][8];

  const int row = tid >> 2, kk = tid & 3;    // 4 threads per GEMV output row
  const int el = tid >> 8, tl = tid & 255;   // element split for per-el ops
  const int wv = tid >> 6, ln = tid & 63;    // wave id / lane id

  // ---- weight staging (R10-proven; weights shared by both elements) ----
  auto stage_qkv = [&](int l) {
    #pragma unroll
    for (int r = 0; r < 6; ++r) {
      int c = (r*8 + wv)*64 + ln;
      int rw = c >> 5, wc = (c & 31) ^ (rw & 7);
      const unsigned short* gp = WB + WOFF_QKV
        + ((size_t)(l*768 + (rw>>5)*256 + s*32 + (rw&31)))*256 + wc*8;
      gl_lds16(gp, Rws + (size_t)(r*8 + wv)*512);
    }
  };
  auto stage_ff1 = [&](int l) {
    #pragma unroll
    for (int r = 0; r < 8; ++r) {
      int c = (r*8 + wv)*64 + ln;
      int rw = c >> 5, wc = (c & 31) ^ (rw & 7);
      const unsigned short* gp = WB + WOFF_F1
        + ((size_t)(l*1024 + s*128 + rw))*256 + wc*8;
      gl_lds16(gp, Rws + (size_t)(r*8 + wv)*512);
    }
  };
  auto stage_ff2 = [&](int l) {
    #pragma unroll
    for (int r = 0; r < 8; ++r) {
      int c = (r*8 + wv)*64 + ln;
      int rw = c >> 4, wc = (c & 15) ^ (rw & 15);
      const unsigned short* gp = WB + WOFF_F2
        + ((size_t)(l*256 + rw))*1024 + s*128 + wc*8;
      gl_lds16(gp, Rws + (size_t)(r*8 + wv)*512);
    }
  };

  // ---- register weight tiles (same rows for both halves) ----
  uint4 pWO[4], pO1[8];
  auto ldWO = [&](int l) {         // o-proj row tl, full own-head k-slice
    const unsigned short* w = WB + WOFF_WO + ((size_t)(l*256 + tl))*256 + s*32;
    #pragma unroll
    for (int c = 0; c < 4; ++c) pWO[c] = *(const uint4*)(w + c*8);
  };
  auto ldO1 = [&]() {              // op_w1 rows (row<128, kk quarter)
    const unsigned short* w = WB + WOFF_OP1 + (size_t)row*256 + kk*64;
    #pragma unroll
    for (int i = 0; i < 8; ++i) pO1[i] = *(const uint4*)(w + i*8);
  };

  // ---- flag-vector barrier (R6-proven) ----
  unsigned int barcount = 0;
  auto gbar = [&]() {
    __syncthreads();
    ++barcount;
    if (tid == 0)
      __hip_atomic_store(flg + s*32, barcount, __ATOMIC_RELEASE, __HIP_MEMORY_SCOPE_AGENT);
    if (tid < GWG) {
      while (__hip_atomic_load(flg + tid*32, __ATOMIC_RELAXED, __HIP_MEMORY_SCOPE_AGENT) < barcount) {}
    }
    if (tid == 0)
      (void)__hip_atomic_load(flg + s*32, __ATOMIC_ACQUIRE, __HIP_MEMORY_SCOPE_AGENT);
    __syncthreads();
  };

  // ---- single-sync dual-element LN stats (waves 0-3 el0, 4-7 el1) ----
  auto lnstats = [&](float v, float* slot, float& m, float& rs) {
    float a = v, b = v * v;
    #pragma unroll
    for (int off = 32; off; off >>= 1) { a += __shfl_xor(a, off); b += __shfl_xor(b, off); }
    if (ln == 0) { slot[wv] = a; slot[8 + wv] = b; }
    __syncthreads();
    int b0 = el*4;
    float sa = slot[b0]+slot[b0+1]+slot[b0+2]+slot[b0+3];
    float sb = slot[8+b0]+slot[9+b0]+slot[10+b0]+slot[11+b0];
    m = sa * (1.0f/256.0f);
    rs = rsqrtf(sb * (1.0f/256.0f) - m*m + 1e-5f);
  };

  // ---- params -> LDS ----
  for (int i = tid; i < 768; i += NTHR) {
    obias[i] = p.sa_o_b[i];
    ff2b[i]  = p.ff2_b[i];
    ln1g[i] = p.ln1_g[i]; ln1b[i] = p.ln1_b[i];
    ln2g[i] = p.ln2_g[i]; ln2b[i] = p.ln2_b[i];
    ln3g[i] = p.ln3_g[i]; ln3b[i] = p.ln3_b[i];
  }
  for (int i = tid; i < 2*768; i += NTHR) {
    int eh = i / 768;
    cals[i] = GRPW[(size_t)(gg*2 + eh) * GRP_STRF + CAL_F + (i % 768)];
  }
  for (int i = tid; i < 288; i += NTHR) {
    int l = i / 96, r = i % 96, sect = (r >> 5), o = r & 31;
    qkvb[i] = p.sa_qkv_b[l*768 + sect*256 + s*32 + o];
  }
  for (int i = tid; i < 384; i += NTHR) {
    int l = i >> 7, o = i & 127;
    ff1b[i] = p.ff1_b[l*1024 + s*128 + o];
  }
  for (int i = tid; i < DDIM*NOUT; i += NTHR) embw[i] = p.emb_w[i];
  for (int i = tid; i < DDIM; i += NTHR) embb[i] = p.emb_b[i];
  for (int i = tid; i < 128; i += NTHR) opb1[i] = p.op_b1[i];
  for (int i = tid; i < NOUT*128; i += NTHR) opw2[i] = p.op_w2[i];
  if (tl < NOUT) OUTV[el][tl] = p.start_token[tl];
  if (tid < 8) opb2[tid] = (tid < NOUT) ? p.op_b2[tid] : 0.f;

  const float divv = expf(-0.035977892078031968f * (float)(2*(tl>>1)));
  __syncthreads();

  // prologue: x(t=0) both elements + stage qkv(0) + WO(0)
  {
    float acc = embb[tl] + ((tl & 1) ? 1.0f : 0.0f);
    #pragma unroll
    for (int j = 0; j < NOUT; ++j) acc += OUTV[el][j] * embw[tl*NOUT + j];
    xls[el][tl] = acc;
  }
  stage_qkv(0);
  ldWO(0);
  __syncthreads();

  for (int t = 0; t < TSEQ; ++t) {
    for (int l = 0; l < NLAY; ++l) {
      // ================= PHASE Q =================
      if (l > 0) {
        float r2 = x2ls[el][tl] + ff2b[(l-1)*256 + tl];
        #pragma unroll
        for (int ss = 0; ss < GWG; ++ss) r2 += PfG[el*2048 + ss*256 + tl];
        float m, rs; lnstats(r2, lred + 0, m, rs);
        xls[el][tl] = (r2 - m) * rs * ln3g[(l-1)*256 + tl] + ln3b[(l-1)*256 + tl];
        __syncthreads();
      }
      // qkv: dual-accumulator GEMV (one weight load, two elements)
      if (row < 96) {
        float aA = 0.f, aB = 0.f;
        #pragma unroll
        for (int i = 0; i < 8; ++i) {
          int ii = (i + kk) & 7;
          int k0 = kk*64 + ii*8;
          const uint4 w = *(const uint4*)(Rws + row*256 + (k0 ^ ((row&7)<<3)));
          aA += dot8(w, xls[0], k0);
          aB += dot8(w, xls[1], k0);
        }
        aA += __shfl_xor(aA, 1); aA += __shfl_xor(aA, 2);
        aB += __shfl_xor(aB, 1); aB += __shfl_xor(aB, 2);
        if (kk == 0) {
          float bq = qkvb[l*96 + row];
          float vA = aA + bq, vB = aB + bq;
          int sect = row >> 5, o = row & 31;
          if (sect == 0) { qb[0][o] = vA; qb[1][o] = vB; }
          else if (sect == 1) {
            kcb[0][(l*TSEQ + t)*34 + o] = f2bf(vA);
            kcb[1][(l*TSEQ + t)*34 + o] = f2bf(vB);
          } else {
            vcb[0][(l*TSEQ + t)*34 + o] = f2bf(vA);
            vcb[1][(l*TSEQ + t)*34 + o] = f2bf(vB);
          }
        }
      }
      __syncthreads();
      stage_ff1(l);              // async; drains by a later sync
      // scores + softmax: wave 0 -> element 0, wave 1 -> element 1
      if (wv < 2) {
        int ee = wv, j = ln;
        float scj = -1e30f;
        if (j <= t) {
          const unsigned short* kr = &kcb[ee][(l*TSEQ + j)*34];
          float a = 0.f;
          #pragma unroll
          for (int c = 0; c < 16; ++c) {
            unsigned int u = *(const unsigned int*)(kr + c*2);
            float lo, hi; bfp(u, lo, hi);
            a += lo*qb[ee][2*c] + hi*qb[ee][2*c + 1];
          }
          scj = a * 0.17677669529663687f;
        }
        float mx = scj;
        #pragma unroll
        for (int off = 32; off; off >>= 1) mx = fmaxf(mx, __shfl_xor(mx, off));
        float e = (j <= t) ? expf(scj - mx) : 0.f;
        float su = e;
        #pragma unroll
        for (int off = 32; off; off >>= 1) su += __shfl_xor(su, off);
        sc[ee][j] = e / su;
      }
      __syncthreads();
      // PV: per-element halves, 8 lanes per d
      {
        int d = tl >> 3, jg = tl & 7;
        float acc = 0.f;
        for (int j = jg; j <= t; j += 8)
          acc += sc[el][j] * bf2f(vcb[el][(l*TSEQ + j)*34 + d]);
        acc += __shfl_xor(acc, 1);
        acc += __shfl_xor(acc, 2);
        acc += __shfl_xor(acc, 4);
        if (jg == 0) ah[el][d] = acc;
      }
      __syncthreads();
      // oproj: full own-head dot per thread (row tl, element el)
      {
        float acc = 0.f;
        #pragma unroll
        for (int c = 0; c < 4; ++c) acc += dot8(pWO[c], ah[el], c*8);
        PoG[el*2048 + s*256 + tl] = acc;
      }
      gbar();   // B1

      // ================= PHASE F =================
      float r = xls[el][tl] + obias[l*256 + tl];
      #pragma unroll
      for (int ss = 0; ss < GWG; ++ss) r += PoG[el*2048 + ss*256 + tl];
      float m1, rs1; lnstats(r, lred + 16, m1, rs1);
      float z = (r - m1)*rs1*ln1g[l*256 + tl] + ln1b[l*256 + tl] + cals[el*768 + l*256 + tl];
      float m2, rs2; lnstats(z, lred + 32, m2, rs2);
      x2ls[el][tl] = (z - m2)*rs2*ln2g[l*256 + tl] + ln2b[l*256 + tl];
      __syncthreads();
      // ff1: dual-accumulator GEMV (128 rows, 4 lanes/row)
      {
        float aA = 0.f, aB = 0.f;
        #pragma unroll
        for (int i = 0; i < 8; ++i) {
          int ii = (i + kk) & 7;
          int k0 = kk*64 + ii*8;
          const uint4 w = *(const uint4*)(Rws + row*256 + (k0 ^ ((row&7)<<3)));
          aA += dot8(w, x2ls[0], k0);
          aB += dot8(w, x2ls[1], k0);
        }
        aA += __shfl_xor(aA, 1); aA += __shfl_xor(aA, 2);
        aB += __shfl_xor(aB, 1); aB += __shfl_xor(aB, 2);
        __syncthreads();           // all ff1 Rws reads done
        stage_ff2(l);              // async
        if (kk == 0) {
          float bf = ff1b[l*128 + row];
          fxl[0][row] = gelu_exact(aA + bf);
          fxl[1][row] = gelu_exact(aB + bf);
        }
      }
      __syncthreads();             // drains ff2 DMA + fxl visible
      // ff2: full own-k-slice dot per thread (row tl, element el)
      {
        float acc2 = 0.f;
        #pragma unroll
        for (int j2 = 0; j2 < 16; ++j2) {
          int k0 = j2*8;
          const uint4 w = *(const uint4*)(Rws + tl*128 + (k0 ^ ((tl&15)<<3)));
          acc2 += dot8(w, fxl[el], k0);
        }
        PfG[el*2048 + s*256 + tl] = acc2;
      }
      __syncthreads();             // ff2 Rws reads done
      {
        int lnx = (l == 2) ? 0 : l + 1;
        stage_qkv(lnx);            // async; drains across B2
        ldWO(lnx);
        if (l == 2) ldO1();
      }
      gbar();   // B2
    } // l

    // ============ STEP TAIL: ln3(l2) + output head + next-step x ========
    {
      float r2 = x2ls[el][tl] + ff2b[2*256 + tl];
      #pragma unroll
      for (int ss = 0; ss < GWG; ++ss) r2 += PfG[el*2048 + ss*256 + tl];
      float m, rs; lnstats(r2, lred + 48, m, rs);
      xls[el][tl] = (r2 - m)*rs*ln3g[2*256 + tl] + ln3b[2*256 + tl];
      __syncthreads();
      // op1: dual-accumulator from register tile
      {
        float aA = 0.f, aB = 0.f;
        #pragma unroll
        for (int i = 0; i < 8; ++i) {
          aA += dot8(pO1[i], xls[0], kk*64 + i*8);
          aB += dot8(pO1[i], xls[1], kk*64 + i*8);
        }
        aA += __shfl_xor(aA, 1); aA += __shfl_xor(aA, 2);
        aB += __shfl_xor(aB, 1); aB += __shfl_xor(aB, 2);
        if (kk == 0) {
          float bo = opb1[row];
          fxl[0][row] = gelu_exact(aA + bo);
          fxl[1][row] = gelu_exact(aB + bo);
        }
      }
      __syncthreads();
      // op2 per element
      if (tl < 192) {
        int oo = tl >> 5, kl = tl & 31;
        float acc = fxl[el][kl]*opw2[oo*128 + kl] + fxl[el][kl+32]*opw2[oo*128 + kl+32]
                  + fxl[el][kl+64]*opw2[oo*128 + kl+64] + fxl[el][kl+96]*opw2[oo*128 + kl+96];
        #pragma unroll
        for (int off = 16; off; off >>= 1) acc += __shfl_xor(acc, off);
        if (kl == 0) {
          float v = acc + opb2[oo];
          OUTV[el][oo] = v;
          if (s == 0) p.out[((size_t)(gg*2 + el)*TSEQ + t)*NOUT + oo] = v;
        }
      }
      __syncthreads();
      // next-step x build (both elements; harmless at t=47)
      {
        float ang = (float)(t + 1) * divv;
        float pe = (tl & 1) ? cosf(ang) : sinf(ang);
        float acc = embb[tl] + pe;
        #pragma unroll
        for (int j = 0; j < NOUT; ++j) acc += OUTV[el][j] * embw[tl*NOUT + j];
        xls[el][tl] = acc;
      }
      __syncthreads();
    }
  } // t
}

extern "C" void kernel_launch(void* const* d_in, const int* in_sizes, int n_in,
                              void* d_out, int out_size, void* d_ws, size_t ws_size,
                              hipStream_t stream) {
  const float* const* F = (const float* const*)d_in;
  const float* z_style = F[0]; const float* z_skill = F[1];
  DecP p;
  p.start_token = F[2];
  const float* mem_w1 = F[3]; const float* mem_b1 = F[4];
  const float* mem_ln_g = F[5]; const float* mem_ln_b = F[6];
  const float* mem_w2 = F[7]; const float* mem_b2 = F[8];
  p.emb_w = F[9]; p.emb_b = F[10];
  const float* sa_qkv_w = F[11]; p.sa_qkv_b = F[12];
  const float* sa_o_w  = F[13]; p.sa_o_b = F[14];
  const float* ca_qkv_w = F[15]; const float* ca_qkv_b = F[16];
  const float* ca_o_w = F[17]; const float* ca_o_b = F[18];
  p.ln1_g = F[19]; p.ln1_b = F[20]; p.ln2_g = F[21]; p.ln2_b = F[22];
  p.ln3_g = F[23]; p.ln3_b = F[24];
  const float* ff1_w = F[25]; p.ff1_b = F[26];
  const float* ff2_w = F[27]; p.ff2_b = F[28];
  const float* op_w1 = F[29]; p.op_b1 = F[30]; p.op_w2 = F[31]; p.op_b2 = F[32];
  p.out = (float*)d_out;
  p.ws  = (unsigned char*)d_ws;

  hipMemsetAsync((char*)d_ws + CNT_OFF, 0, CNT_BYTES, stream);
  convert_bf16<<<dim3(512), dim3(256), 0, stream>>>(sa_qkv_w, sa_o_w, ff1_w, ff2_w, op_w1,
                                                    (unsigned char*)d_ws);
  precompute_ca<<<dim3(48), dim3(256), 0, stream>>>(z_style, z_skill, mem_w1, mem_b1,
                                                    mem_ln_g, mem_ln_b, mem_w2, mem_b2,
                                                    ca_qkv_w, ca_qkv_b, ca_o_w, ca_o_b,
                                                    (unsigned char*)d_ws);
  decoder_persistent<<<dim3(NBLK), dim3(NTHR), 0, stream>>>(p);
}

// Round 15
// 2535.644 us; speedup vs baseline: 3.1598x; 1.0632x over previous
//
#include <hip/hip_runtime.h>
#include <hip/hip_bf16.h>
#include <math.h>

// ---------------- problem constants ----------------
#define NGRP 16     // batch groups (one per batch element)
#define GWG  8      // workgroups per group (= heads)
#define NBLK (NGRP*GWG)   // 128
#define NTHR 512
#define TSEQ 48
#define DDIM 256
#define HDIM 32
#define NLAY 3
#define NOUT 6

// ---------------- ws layout ----------------
#define CNT_OFF   0u
#define CNT_BYTES 16384u         // 16 groups x 8 flag slots x 128B
#define GRP_OFF   16384u
#define GRP_STRF  5120u          // floats per group block
#define PO_F   0                 // [8*256] oproj partials
#define PF_F   2048              // [8*256] ff2 partials
#define CAL_F  4096              // [3*256] cross-attn constants
#define WB_OFF 360448u           // bf16 weights (element offsets below)
#define WOFF_QKV 0u
#define WOFF_WO  589824u
#define WOFF_F1  786432u
#define WOFF_F2  1572864u
#define WOFF_OP1 2359296u
#define NCVT     2392064u

typedef __attribute__((address_space(1))) const unsigned int gu32;
typedef __attribute__((address_space(3))) unsigned int lu32;

__device__ __forceinline__ void gl_lds16(const unsigned short* g, unsigned short* l) {
  __builtin_amdgcn_global_load_lds((gu32*)g, (lu32*)l, 16, 0, 0);
}
__device__ __forceinline__ void bfp(unsigned int u, float& lo, float& hi) {
  union { unsigned int i; float f; } a, b;
  a.i = u << 16; b.i = u & 0xffff0000u; lo = a.f; hi = b.f;
}
__device__ __forceinline__ float gelu_exact(float x) {
  return 0.5f * x * (1.0f + erff(x * 0.70710678118654752f));
}
__device__ __forceinline__ float dot8(const uint4& u, const float* x, int k0) {
  float lo, hi, acc = 0.f;
  bfp(u.x, lo, hi); acc += x[k0  ]*lo + x[k0+1]*hi;
  bfp(u.y, lo, hi); acc += x[k0+2]*lo + x[k0+3]*hi;
  bfp(u.z, lo, hi); acc += x[k0+4]*lo + x[k0+5]*hi;
  bfp(u.w, lo, hi); acc += x[k0+6]*lo + x[k0+7]*hi;
  return acc;
}

// ---------------- weight fp32 -> bf16 ----------------
__global__ void convert_bf16(const float* qkv, const float* ow, const float* f1,
                             const float* f2, const float* w1, unsigned char* ws) {
  __hip_bfloat16* dst = (__hip_bfloat16*)(ws + WB_OFF);
  size_t stride = (size_t)gridDim.x * blockDim.x;
  for (size_t i = (size_t)blockIdx.x * blockDim.x + threadIdx.x; i < NCVT; i += stride) {
    float v;
    if      (i < WOFF_WO)  v = qkv[i];
    else if (i < WOFF_F1)  v = ow[i - WOFF_WO];
    else if (i < WOFF_F2)  v = f1[i - WOFF_F1];
    else if (i < WOFF_OP1) v = f2[i - WOFF_F2];
    else                   v = w1[i - WOFF_OP1];
    dst[i] = __float2bfloat16(v);
  }
}

// ---------------- one-shot per-(g,l): memvec chain + cross-attn const ----------------
__global__ void precompute_ca(const float* zs, const float* zk,
                              const float* mw1, const float* mb1,
                              const float* mlg, const float* mlb,
                              const float* mw2, const float* mb2,
                              const float* cqw, const float* cqb,
                              const float* cow, const float* cob,
                              unsigned char* ws) {
  const int g = blockIdx.x & 15, l = blockIdx.x >> 4;
  const int tid = threadIdx.x;           // 256 threads
  __shared__ float cond[128], h[256], mvv[256], vv[256], lred[16];

  auto lnstat = [&](float v, float& m, float& rs) {
    float a = v, b = v * v;
    #pragma unroll
    for (int off = 32; off; off >>= 1) { a += __shfl_xor(a, off); b += __shfl_xor(b, off); }
    if ((tid & 63) == 0) { lred[tid >> 6] = a; lred[4 + (tid >> 6)] = b; }
    __syncthreads();
    float sa = lred[0]+lred[1]+lred[2]+lred[3];
    float sb = lred[4]+lred[5]+lred[6]+lred[7];
    m = sa * (1.0f/256.0f);
    rs = rsqrtf(sb * (1.0f/256.0f) - m*m + 1e-5f);
    __syncthreads();
  };

  if (tid < 128) cond[tid] = (tid < 64) ? zs[g*64 + tid] : zk[g*64 + tid - 64];
  __syncthreads();
  float acc = mb1[tid];
  { const float* w = mw1 + (size_t)tid * 128;
    for (int k = 0; k < 128; k += 4) {
      float4 q = *(const float4*)(w + k);
      acc += q.x*cond[k] + q.y*cond[k+1] + q.z*cond[k+2] + q.w*cond[k+3];
    } }
  float m, rs; lnstat(acc, m, rs);
  h[tid] = gelu_exact((acc - m) * rs * mlg[tid] + mlb[tid]);
  __syncthreads();
  float a2 = mb2[tid];
  { const float* w = mw2 + (size_t)tid * 256;
    for (int k = 0; k < 256; k += 4) {
      float4 q = *(const float4*)(w + k);
      a2 += q.x*h[k] + q.y*h[k+1] + q.z*h[k+2] + q.w*h[k+3];
    } }
  mvv[tid] = a2;
  __syncthreads();
  float a3 = cqb[l*768 + 512 + tid];
  { const float* w = cqw + ((size_t)l*768 + 512 + tid) * 256;
    for (int k = 0; k < 256; k += 4) {
      float4 q = *(const float4*)(w + k);
      a3 += q.x*mvv[k] + q.y*mvv[k+1] + q.z*mvv[k+2] + q.w*mvv[k+3];
    } }
  vv[tid] = a3;
  __syncthreads();
  float a4 = cob[l*256 + tid];
  { const float* w = cow + ((size_t)l*256 + tid) * 256;
    for (int k = 0; k < 256; k += 4) {
      float4 q = *(const float4*)(w + k);
      a4 += q.x*vv[k] + q.y*vv[k+1] + q.z*vv[k+2] + q.w*vv[k+3];
    } }
  ((float*)(ws + GRP_OFF))[(size_t)g * GRP_STRF + CAL_F + l*256 + tid] = a4;
}

struct DecP {
  const float *start_token, *emb_w, *emb_b;
  const float *sa_qkv_b, *sa_o_b;
  const float *ln1_g, *ln1_b, *ln2_g, *ln2_b, *ln3_g, *ln3_b;
  const float *ff1_b, *ff2_b;
  const float *op_b1, *op_w2, *op_b2;
  float* out;
  unsigned char* ws;
};

// Persistent decoder: R10 base (best, 2037us) + stage_qkv in B2 barrier shadow +
// full-dot oproj/ff2 (-2 syncs/layer) + float4 K-dot (K cache stride 40).
__global__ __launch_bounds__(NTHR, 1) void decoder_persistent(DecP p) {
  const int g = blockIdx.x % NGRP;
  const int s = blockIdx.x / NGRP;     // head / ff-slice id 0..7
  const int tid = threadIdx.x;

  unsigned int* flg = (unsigned int*)(p.ws + CNT_OFF) + (size_t)g * 256;  // 8 slots x 128B
  float* grp = (float*)(p.ws + GRP_OFF) + (size_t)g * GRP_STRF;
  float* Po = grp + PO_F;
  float* Pf = grp + PF_F;
  const float* CALW = grp + CAL_F;
  const unsigned short* WB = (const unsigned short*)(p.ws + WB_OFF);

  __shared__ __align__(16) unsigned short Rws[32768];   // 64KB weight stage region
  __shared__ float xls[DDIM], x2ls[DDIM], lred[32], fxl[128];
  __shared__ float qb[HDIM], ah[HDIM], sc[64];
  __shared__ __align__(16) float kc[NLAY*TSEQ*40];   // stride 40: 160B rows, 16B-aligned
  __shared__ float vc[NLAY*TSEQ*33];                 // stride 33 (scalar PV reads)
  __shared__ float cals[768], obias[768], ff2b[768];
  __shared__ float ln1g[768], ln1b[768], ln2g[768], ln2b[768], ln3g[768], ln3b[768];
  __shared__ float qkvb[288], ff1b[384];
  __shared__ float embw[DDIM*NOUT], embb[DDIM];
  __shared__ float opb1[128], opw2[NOUT*128], opb2[8], OUTV[8];

  const int row = tid >> 2, kk = tid & 3;    // 4 threads per GEMV output row
  const int wv = tid >> 6, ln = tid & 63;    // wave id / lane id

  // ---- weight staging (async DMA; swizzled source gather, linear LDS dest) ----
  auto stage_qkv = [&](int l) {     // 96 rows x 512B, 8-slot swizzle
    #pragma unroll
    for (int r = 0; r < 6; ++r) {
      int c = (r*8 + wv)*64 + ln;
      int rw = c >> 5, wc = (c & 31) ^ (rw & 7);
      const unsigned short* gp = WB + WOFF_QKV
        + ((size_t)(l*768 + (rw>>5)*256 + s*32 + (rw&31)))*256 + wc*8;
      gl_lds16(gp, Rws + (size_t)(r*8 + wv)*512);
    }
  };
  auto stage_ff1 = [&](int l) {     // 128 rows x 512B, 8-slot swizzle
    #pragma unroll
    for (int r = 0; r < 8; ++r) {
      int c = (r*8 + wv)*64 + ln;
      int rw = c >> 5, wc = (c & 31) ^ (rw & 7);
      const unsigned short* gp = WB + WOFF_F1
        + ((size_t)(l*1024 + s*128 + rw))*256 + wc*8;
      gl_lds16(gp, Rws + (size_t)(r*8 + wv)*512);
    }
  };
  auto stage_ff2 = [&](int l) {     // 256 rows x 256B, 16-slot swizzle
    #pragma unroll
    for (int r = 0; r < 8; ++r) {
      int c = (r*8 + wv)*64 + ln;
      int rw = c >> 4, wc = (c & 15) ^ (rw & 15);
      const unsigned short* gp = WB + WOFF_F2
        + ((size_t)(l*256 + rw))*1024 + s*128 + wc*8;
      gl_lds16(gp, Rws + (size_t)(r*8 + wv)*512);
    }
  };

  // ---- small register tiles ----
  uint4 pWO[4], pO1[8];
  auto ldWO = [&](int l) {         // o-proj row tid (tid<256), full own-head k-slice
    if (tid < 256) {
      const unsigned short* w = WB + WOFF_WO + ((size_t)(l*256 + tid))*256 + s*32;
      #pragma unroll
      for (int c = 0; c < 4; ++c) pWO[c] = *(const uint4*)(w + c*8);
    }
  };
  auto ldO1 = [&]() {              // op_w1 rows (row, kk quarter)
    const unsigned short* w = WB + WOFF_OP1 + (size_t)row*256 + kk*64;
    #pragma unroll
    for (int i = 0; i < 8; ++i) pO1[i] = *(const uint4*)(w + i*8);
  };

  // ---- flag-vector barrier; optional stager issues in the barrier shadow ----
  unsigned int barcount = 0;
  auto gbar = [&](auto stager) {
    __syncthreads();
    ++barcount;
    if (tid == 0)
      __hip_atomic_store(flg + s*32, barcount, __ATOMIC_RELEASE, __HIP_MEMORY_SCOPE_AGENT);
    stager();          // async DMA issued here; closing __syncthreads drains during spin
    if (tid < GWG) {
      while (__hip_atomic_load(flg + tid*32, __ATOMIC_RELAXED, __HIP_MEMORY_SCOPE_AGENT) < barcount) {}
    }
    if (tid == 0)
      (void)__hip_atomic_load(flg + s*32, __ATOMIC_ACQUIRE, __HIP_MEMORY_SCOPE_AGENT);
    __syncthreads();
  };
  auto gbar0 = [&]() { gbar([]{}); };

  // ---- single-sync LN stats, per-site slots ----
  auto lnstats = [&](float v, float* slot, float& m, float& rs) {
    float a = v, b = v * v;
    #pragma unroll
    for (int off = 32; off; off >>= 1) { a += __shfl_xor(a, off); b += __shfl_xor(b, off); }
    if ((tid & 63) == 0 && tid < 256) { slot[tid >> 6] = a; slot[4 + (tid >> 6)] = b; }
    __syncthreads();
    float sa = slot[0]+slot[1]+slot[2]+slot[3];
    float sb = slot[4]+slot[5]+slot[6]+slot[7];
    m = sa * (1.0f/256.0f);
    rs = rsqrtf(sb * (1.0f/256.0f) - m*m + 1e-5f);
  };

  // ---- small params -> LDS ----
  for (int i = tid; i < 768; i += NTHR) {
    cals[i]  = CALW[i];
    obias[i] = p.sa_o_b[i];
    ff2b[i]  = p.ff2_b[i];
    ln1g[i] = p.ln1_g[i]; ln1b[i] = p.ln1_b[i];
    ln2g[i] = p.ln2_g[i]; ln2b[i] = p.ln2_b[i];
    ln3g[i] = p.ln3_g[i]; ln3b[i] = p.ln3_b[i];
  }
  for (int i = tid; i < 288; i += NTHR) {
    int l = i / 96, r = i % 96, sect = (r >> 5), o = r & 31;
    qkvb[i] = p.sa_qkv_b[l*768 + sect*256 + s*32 + o];
  }
  for (int i = tid; i < 384; i += NTHR) {
    int l = i >> 7, o = i & 127;
    ff1b[i] = p.ff1_b[l*1024 + s*128 + o];
  }
  for (int i = tid; i < DDIM*NOUT; i += NTHR) embw[i] = p.emb_w[i];
  for (int i = tid; i < DDIM; i += NTHR) embb[i] = p.emb_b[i];
  for (int i = tid; i < 128; i += NTHR) opb1[i] = p.op_b1[i];
  for (int i = tid; i < NOUT*128; i += NTHR) opw2[i] = p.op_w2[i];
  if (tid < NOUT) OUTV[tid] = p.start_token[tid];
  if (tid < 8) opb2[tid] = (tid < NOUT) ? p.op_b2[tid] : 0.f;

  const float divv = (tid < 256) ? expf(-0.035977892078031968f * (float)(2*(tid>>1))) : 0.f;
  __syncthreads();

  // prologue: x(t=0) + stage qkv(0) + WO(0)
  if (tid < 256) {
    float acc = embb[tid] + ((tid & 1) ? 1.0f : 0.0f);   // pe(t=0): sin0=0, cos0=1
    #pragma unroll
    for (int j = 0; j < NOUT; ++j) acc += OUTV[j] * embw[tid*NOUT + j];
    xls[tid] = acc;
  }
  stage_qkv(0);
  ldWO(0);
  __syncthreads();   // drains DMA + xls

  for (int t = 0; t < TSEQ; ++t) {
    for (int l = 0; l < NLAY; ++l) {
      // ================= PHASE Q =================
      if (l > 0) {
        float r2 = 0.f;
        if (tid < 256) {
          r2 = x2ls[tid] + ff2b[(l-1)*256 + tid];
          #pragma unroll
          for (int ss = 0; ss < GWG; ++ss) r2 += Pf[ss*256 + tid];
        }
        float m, rs; lnstats(r2, lred + 0, m, rs);
        if (tid < 256)
          xls[tid] = (r2 - m) * rs * ln3g[(l-1)*256 + tid] + ln3b[(l-1)*256 + tid];
        __syncthreads();
      }
      // qkv GEMV (staged LDS, 4 lanes/row, shuffle reduce)
      if (row < 96) {
        float acc = 0.f;
        #pragma unroll
        for (int i = 0; i < 8; ++i) {
          int ii = (i + kk) & 7;
          int k0 = kk*64 + ii*8;
          const uint4 w = *(const uint4*)(Rws + row*256 + (k0 ^ ((row&7)<<3)));
          acc += dot8(w, xls, k0);
        }
        acc += __shfl_xor(acc, 1);
        acc += __shfl_xor(acc, 2);
        if (kk == 0) {
          float v = acc + qkvb[l*96 + row];
          int sect = row >> 5, o = row & 31;
          if (sect == 0) qb[o] = v;
          else if (sect == 1) kc[(l*TSEQ + t)*40 + o] = v;
          else vc[(l*TSEQ + t)*33 + o] = v;
        }
      }
      __syncthreads();           // qkv Rws reads done; qb/kc/vc visible
      stage_ff1(l);              // async; hidden under attention (R10-proven placement)
      // scores + softmax (wave 0 only; float4 K reads)
      if (tid < 64) {
        float scj = -1e30f;
        if (tid <= t) {
          const float4* kr = (const float4*)&kc[(l*TSEQ + tid)*40];
          float a = 0.f;
          #pragma unroll
          for (int d0 = 0; d0 < 8; ++d0) {
            float4 kq = kr[d0];
            a += kq.x*qb[d0*4] + kq.y*qb[d0*4+1] + kq.z*qb[d0*4+2] + kq.w*qb[d0*4+3];
          }
          scj = a * 0.17677669529663687f;
        }
        float mx = scj;
        #pragma unroll
        for (int off = 32; off; off >>= 1) mx = fmaxf(mx, __shfl_xor(mx, off));
        float e = (tid <= t) ? expf(scj - mx) : 0.f;
        float su = e;
        #pragma unroll
        for (int off = 32; off; off >>= 1) su += __shfl_xor(su, off);
        sc[tid] = e / su;
      }
      __syncthreads();
      // PV: 256 threads, 8 lanes per d
      if (tid < 256) {
        int d = tid >> 3, jg = tid & 7;
        float acc = 0.f;
        for (int j = jg; j <= t; j += 8) acc += sc[j] * vc[(l*TSEQ + j)*33 + d];
        acc += __shfl_xor(acc, 1);
        acc += __shfl_xor(acc, 2);
        acc += __shfl_xor(acc, 4);
        if (jg == 0) ah[d] = acc;
      }
      __syncthreads();
      // oproj: full own-head dot per thread (tid<256) -> Po directly (no red/sync)
      if (tid < 256) {
        float acc = 0.f;
        #pragma unroll
        for (int c = 0; c < 4; ++c) acc += dot8(pWO[c], ah, c*8);
        Po[s*256 + tid] = acc;
      }
      gbar0();   // B1

      // ================= PHASE F =================
      float r = 0.f;
      if (tid < 256) {
        r = xls[tid] + obias[l*256 + tid];
        #pragma unroll
        for (int ss = 0; ss < GWG; ++ss) r += Po[ss*256 + tid];
      }
      float m1, rs1; lnstats(r, lred + 8, m1, rs1);
      float z = 0.f;
      if (tid < 256)
        z = (r - m1)*rs1*ln1g[l*256 + tid] + ln1b[l*256 + tid] + cals[l*256 + tid];
      float m2, rs2; lnstats(z, lred + 16, m2, rs2);
      if (tid < 256) x2ls[tid] = (z - m2)*rs2*ln2g[l*256 + tid] + ln2b[l*256 + tid];
      __syncthreads();
      // ff1 GEMV (staged LDS, 4 lanes/row, shuffle reduce)
      float facc = 0.f;
      {
        #pragma unroll
        for (int i = 0; i < 8; ++i) {
          int ii = (i + kk) & 7;
          int k0 = kk*64 + ii*8;
          const uint4 w = *(const uint4*)(Rws + row*256 + (k0 ^ ((row&7)<<3)));
          facc += dot8(w, x2ls, k0);
        }
        facc += __shfl_xor(facc, 1);
        facc += __shfl_xor(facc, 2);
      }
      __syncthreads();             // all ff1 Rws reads done
      stage_ff2(l);                // async; gelu overlaps part of it
      if (kk == 0) fxl[row] = gelu_exact(facc + ff1b[l*128 + row]);
      __syncthreads();             // drains ff2 DMA + fxl visible
      // ff2: full own-k-slice dot per thread (tid<256), 16-slot swizzle -> Pf
      if (tid < 256) {
        float acc2 = 0.f;
        #pragma unroll
        for (int j2 = 0; j2 < 16; ++j2) {
          int k0 = j2*8;
          const uint4 w = *(const uint4*)(Rws + tid*128 + (k0 ^ ((tid&15)<<3)));
          acc2 += dot8(w, fxl, k0);
        }
        Pf[s*256 + tid] = acc2;
      }
      {
        int lnx = (l == 2) ? 0 : l + 1;
        ldWO(lnx);                 // register loads: compiler schedules across barrier
        if (l == 2) ldO1();
        gbar([&]{ stage_qkv(lnx); });   // B2: qkv DMA issued in barrier shadow
      }
    } // l

    // ============ STEP TAIL: ln3(l2) + output head + next-step x, all WGs ========
    {
      float r2 = 0.f;
      if (tid < 256) {
        r2 = x2ls[tid] + ff2b[2*256 + tid];
        #pragma unroll
        for (int ss = 0; ss < GWG; ++ss) r2 += Pf[ss*256 + tid];
      }
      float m, rs; lnstats(r2, lred + 24, m, rs);
      if (tid < 256) xls[tid] = (r2 - m)*rs*ln3g[2*256 + tid] + ln3b[2*256 + tid];
      __syncthreads();
      // op1 (register tile, 4 lanes/row, shuffle reduce)
      float oacc = 0.f;
      #pragma unroll
      for (int i = 0; i < 8; ++i) oacc += dot8(pO1[i], xls, kk*64 + i*8);
      oacc += __shfl_xor(oacc, 1);
      oacc += __shfl_xor(oacc, 2);
      if (kk == 0) fxl[row] = gelu_exact(oacc + opb1[row]);
      __syncthreads();
      // op2
      if (tid < 192) {
        int oo = tid >> 5, kl = tid & 31;
        float acc = fxl[kl]*opw2[oo*128 + kl] + fxl[kl+32]*opw2[oo*128 + kl+32]
                  + fxl[kl+64]*opw2[oo*128 + kl+64] + fxl[kl+96]*opw2[oo*128 + kl+96];
        #pragma unroll
        for (int off = 16; off; off >>= 1) acc += __shfl_xor(acc, off);
        if (kl == 0) {
          float v = acc + opb2[oo];
          OUTV[oo] = v;
          if (s == 0) p.out[((size_t)g*TSEQ + t)*NOUT + oo] = v;
        }
      }
      __syncthreads();
      // next-step x build (harmless at t=47)
      if (tid < 256) {
        float ang = (float)(t + 1) * divv;
        float pe = (tid & 1) ? cosf(ang) : sinf(ang);
        float acc = embb[tid] + pe;
        #pragma unroll
        for (int j = 0; j < NOUT; ++j) acc += OUTV[j] * embw[tid*NOUT + j];
        xls[tid] = acc;
      }
      __syncthreads();
    }
  } // t
}

extern "C" void kernel_launch(void* const* d_in, const int* in_sizes, int n_in,
                              void* d_out, int out_size, void* d_ws, size_t ws_size,
                              hipStream_t stream) {
  const float* const* F = (const float* const*)d_in;
  const float* z_style = F[0]; const float* z_skill = F[1];
  DecP p;
  p.start_token = F[2];
  const float* mem_w1 = F[3]; const float* mem_b1 = F[4];
  const float* mem_ln_g = F[5]; const float* mem_ln_b = F[6];
  const float* mem_w2 = F[7]; const float* mem_b2 = F[8];
  p.emb_w = F[9]; p.emb_b = F[10];
  const float* sa_qkv_w = F[11]; p.sa_qkv_b = F[12];
  const float* sa_o_w  = F[13]; p.sa_o_b = F[14];
  const float* ca_qkv_w = F[15]; const float* ca_qkv_b = F[16];
  const float* ca_o_w = F[17]; const float* ca_o_b = F[18];
  p.ln1_g = F[19]; p.ln1_b = F[20]; p.ln2_g = F[21]; p.ln2_b = F[22];
  p.ln3_g = F[23]; p.ln3_b = F[24];
  const float* ff1_w = F[25]; p.ff1_b = F[26];
  const float* ff2_w = F[27]; p.ff2_b = F[28];
  const float* op_w1 = F[29]; p.op_b1 = F[30]; p.op_w2 = F[31]; p.op_b2 = F[32];
  p.out = (float*)d_out;
  p.ws  = (unsigned char*)d_ws;

  hipMemsetAsync((char*)d_ws + CNT_OFF, 0, CNT_BYTES, stream);
  convert_bf16<<<dim3(512), dim3(256), 0, stream>>>(sa_qkv_w, sa_o_w, ff1_w, ff2_w, op_w1,
                                                    (unsigned char*)d_ws);
  precompute_ca<<<dim3(48), dim3(256), 0, stream>>>(z_style, z_skill, mem_w1, mem_b1,
                                                    mem_ln_g, mem_ln_b, mem_w2, mem_b2,
                                                    ca_qkv_w, ca_qkv_b, ca_o_w, ca_o_b,
                                                    (unsigned char*)d_ws);
  decoder_persistent<<<dim3(NBLK), dim3(NTHR), 0, stream>>>(p);
}

// Round 16
// 2036.395 us; speedup vs baseline: 3.9344x; 1.2452x over previous
//
#include <hip/hip_runtime.h>
#include <hip/hip_bf16.h>
#include <math.h>

// ---------------- problem constants ----------------
#define NGRP 16     // batch groups (one per batch element)
#define GWG  8      // workgroups per group (= heads)
#define NBLK (NGRP*GWG)   // 128
#define NTHR 512
#define TSEQ 48
#define DDIM 256
#define HDIM 32
#define NLAY 3
#define NOUT 6

// ---------------- ws layout ----------------
#define CNT_OFF   0u
#define CNT_BYTES 16384u         // 16 groups x 8 flag slots x 128B
#define GRP_OFF   16384u
#define GRP_STRF  5120u          // floats per group block
#define PO_F   0                 // [8*256] oproj partials
#define PF_F   2048              // [8*256] ff2 partials
#define CAL_F  4096              // [3*256] cross-attn constants
#define WB_OFF 360448u           // bf16 weights (element offsets below)
#define WOFF_QKV 0u
#define WOFF_WO  589824u
#define WOFF_F1  786432u
#define WOFF_F2  1572864u
#define WOFF_OP1 2359296u
#define NCVT     2392064u

typedef __attribute__((address_space(1))) const unsigned int gu32;
typedef __attribute__((address_space(3))) unsigned int lu32;

__device__ __forceinline__ void gl_lds16(const unsigned short* g, unsigned short* l) {
  __builtin_amdgcn_global_load_lds((gu32*)g, (lu32*)l, 16, 0, 0);
}
__device__ __forceinline__ void bfp(unsigned int u, float& lo, float& hi) {
  union { unsigned int i; float f; } a, b;
  a.i = u << 16; b.i = u & 0xffff0000u; lo = a.f; hi = b.f;
}
__device__ __forceinline__ float gelu_exact(float x) {
  return 0.5f * x * (1.0f + erff(x * 0.70710678118654752f));
}
__device__ __forceinline__ float dot8(const uint4& u, const float* x, int k0) {
  float lo, hi, acc = 0.f;
  bfp(u.x, lo, hi); acc += x[k0  ]*lo + x[k0+1]*hi;
  bfp(u.y, lo, hi); acc += x[k0+2]*lo + x[k0+3]*hi;
  bfp(u.z, lo, hi); acc += x[k0+4]*lo + x[k0+5]*hi;
  bfp(u.w, lo, hi); acc += x[k0+6]*lo + x[k0+7]*hi;
  return acc;
}

// ---------------- weight fp32 -> bf16 ----------------
__global__ void convert_bf16(const float* qkv, const float* ow, const float* f1,
                             const float* f2, const float* w1, unsigned char* ws) {
  __hip_bfloat16* dst = (__hip_bfloat16*)(ws + WB_OFF);
  size_t stride = (size_t)gridDim.x * blockDim.x;
  for (size_t i = (size_t)blockIdx.x * blockDim.x + threadIdx.x; i < NCVT; i += stride) {
    float v;
    if      (i < WOFF_WO)  v = qkv[i];
    else if (i < WOFF_F1)  v = ow[i - WOFF_WO];
    else if (i < WOFF_F2)  v = f1[i - WOFF_F1];
    else if (i < WOFF_OP1) v = f2[i - WOFF_F2];
    else                   v = w1[i - WOFF_OP1];
    dst[i] = __float2bfloat16(v);
  }
}

// ---------------- one-shot per-(g,l): memvec chain + cross-attn const ----------------
__global__ void precompute_ca(const float* zs, const float* zk,
                              const float* mw1, const float* mb1,
                              const float* mlg, const float* mlb,
                              const float* mw2, const float* mb2,
                              const float* cqw, const float* cqb,
                              const float* cow, const float* cob,
                              unsigned char* ws) {
  const int g = blockIdx.x & 15, l = blockIdx.x >> 4;
  const int tid = threadIdx.x;           // 256 threads
  __shared__ float cond[128], h[256], mvv[256], vv[256], lred[16];

  auto lnstat = [&](float v, float& m, float& rs) {
    float a = v, b = v * v;
    #pragma unroll
    for (int off = 32; off; off >>= 1) { a += __shfl_xor(a, off); b += __shfl_xor(b, off); }
    if ((tid & 63) == 0) { lred[tid >> 6] = a; lred[4 + (tid >> 6)] = b; }
    __syncthreads();
    float sa = lred[0]+lred[1]+lred[2]+lred[3];
    float sb = lred[4]+lred[5]+lred[6]+lred[7];
    m = sa * (1.0f/256.0f);
    rs = rsqrtf(sb * (1.0f/256.0f) - m*m + 1e-5f);
    __syncthreads();
  };

  if (tid < 128) cond[tid] = (tid < 64) ? zs[g*64 + tid] : zk[g*64 + tid - 64];
  __syncthreads();
  float acc = mb1[tid];
  { const float* w = mw1 + (size_t)tid * 128;
    for (int k = 0; k < 128; k += 4) {
      float4 q = *(const float4*)(w + k);
      acc += q.x*cond[k] + q.y*cond[k+1] + q.z*cond[k+2] + q.w*cond[k+3];
    } }
  float m, rs; lnstat(acc, m, rs);
  h[tid] = gelu_exact((acc - m) * rs * mlg[tid] + mlb[tid]);
  __syncthreads();
  float a2 = mb2[tid];
  { const float* w = mw2 + (size_t)tid * 256;
    for (int k = 0; k < 256; k += 4) {
      float4 q = *(const float4*)(w + k);
      a2 += q.x*h[k] + q.y*h[k+1] + q.z*h[k+2] + q.w*h[k+3];
    } }
  mvv[tid] = a2;
  __syncthreads();
  float a3 = cqb[l*768 + 512 + tid];
  { const float* w = cqw + ((size_t)l*768 + 512 + tid) * 256;
    for (int k = 0; k < 256; k += 4) {
      float4 q = *(const float4*)(w + k);
      a3 += q.x*mvv[k] + q.y*mvv[k+1] + q.z*mvv[k+2] + q.w*mvv[k+3];
    } }
  vv[tid] = a3;
  __syncthreads();
  float a4 = cob[l*256 + tid];
  { const float* w = cow + ((size_t)l*256 + tid) * 256;
    for (int k = 0; k < 256; k += 4) {
      float4 q = *(const float4*)(w + k);
      a4 += q.x*vv[k] + q.y*vv[k+1] + q.z*vv[k+2] + q.w*vv[k+3];
    } }
  ((float*)(ws + GRP_OFF))[(size_t)g * GRP_STRF + CAL_F + l*256 + tid] = a4;
}

struct DecP {
  const float *start_token, *emb_w, *emb_b;
  const float *sa_qkv_b, *sa_o_b;
  const float *ln1_g, *ln1_b, *ln2_g, *ln2_b, *ln3_g, *ln3_b;
  const float *ff1_b, *ff2_b;
  const float *op_b1, *op_w2, *op_b2;
  float* out;
  unsigned char* ws;
};

// Persistent decoder: R7 structure + shuffle-reduce qkv/ff1, single-sync lnstats,
// 16-slot ff2 swizzle, fused tail x-build. (= R10, best verified config: 2037us)
__global__ __launch_bounds__(NTHR, 1) void decoder_persistent(DecP p) {
  const int g = blockIdx.x % NGRP;
  const int s = blockIdx.x / NGRP;     // head / ff-slice id 0..7
  const int tid = threadIdx.x;

  unsigned int* flg = (unsigned int*)(p.ws + CNT_OFF) + (size_t)g * 256;  // 8 slots x 128B
  float* grp = (float*)(p.ws + GRP_OFF) + (size_t)g * GRP_STRF;
  float* Po = grp + PO_F;
  float* Pf = grp + PF_F;
  const float* CALW = grp + CAL_F;
  const unsigned short* WB = (const unsigned short*)(p.ws + WB_OFF);

  __shared__ __align__(16) unsigned short Rws[32768];   // 64KB weight stage region
  __shared__ float xls[DDIM], x2ls[DDIM], red[NTHR], lred[32], fxl[128];
  __shared__ float qb[HDIM], ah[HDIM], sc[64];
  __shared__ float kc[NLAY*TSEQ*33], vc[NLAY*TSEQ*33];   // padded stride 33
  __shared__ float cals[768], obias[768], ff2b[768];
  __shared__ float ln1g[768], ln1b[768], ln2g[768], ln2b[768], ln3g[768], ln3b[768];
  __shared__ float qkvb[288], ff1b[384];
  __shared__ float embw[DDIM*NOUT], embb[DDIM];
  __shared__ float opb1[128], opw2[NOUT*128], opb2[8], OUTV[8];

  const int row = tid >> 2, kk = tid & 3;    // 4 threads per GEMV output row
  const int oB = tid & 255, khB = tid >> 8;  // 2 threads per output row (oproj/ff2)
  const int wv = tid >> 6, ln = tid & 63;    // wave id / lane id

  // ---- weight staging (async DMA; swizzled source gather, linear LDS dest) ----
  auto stage_qkv = [&](int l) {     // 96 rows x 512B, 8-slot swizzle
    #pragma unroll
    for (int r = 0; r < 6; ++r) {
      int c = (r*8 + wv)*64 + ln;
      int rw = c >> 5, wc = (c & 31) ^ (rw & 7);
      const unsigned short* gp = WB + WOFF_QKV
        + ((size_t)(l*768 + (rw>>5)*256 + s*32 + (rw&31)))*256 + wc*8;
      gl_lds16(gp, Rws + (size_t)(r*8 + wv)*512);
    }
  };
  auto stage_ff1 = [&](int l) {     // 128 rows x 512B, 8-slot swizzle
    #pragma unroll
    for (int r = 0; r < 8; ++r) {
      int c = (r*8 + wv)*64 + ln;
      int rw = c >> 5, wc = (c & 31) ^ (rw & 7);
      const unsigned short* gp = WB + WOFF_F1
        + ((size_t)(l*1024 + s*128 + rw))*256 + wc*8;
      gl_lds16(gp, Rws + (size_t)(r*8 + wv)*512);
    }
  };
  auto stage_ff2 = [&](int l) {     // 256 rows x 256B, 16-slot swizzle
    #pragma unroll
    for (int r = 0; r < 8; ++r) {
      int c = (r*8 + wv)*64 + ln;
      int rw = c >> 4, wc = (c & 15) ^ (rw & 15);
      const unsigned short* gp = WB + WOFF_F2
        + ((size_t)(l*256 + rw))*1024 + s*128 + wc*8;
      gl_lds16(gp, Rws + (size_t)(r*8 + wv)*512);
    }
  };

  // ---- small register tiles (R7 layout) ----
  uint4 pWO[2], pO1[8];
  auto ldWO = [&](int l) {         // o-proj rows oB, k-half khB of own head
    const unsigned short* w = WB + WOFF_WO + ((size_t)(l*256 + oB))*256 + s*32 + khB*16;
    pWO[0] = *(const uint4*)(w);
    pWO[1] = *(const uint4*)(w + 8);
  };
  auto ldO1 = [&]() {              // op_w1 rows (row, kk quarter)
    const unsigned short* w = WB + WOFF_OP1 + (size_t)row*256 + kk*64;
    #pragma unroll
    for (int i = 0; i < 8; ++i) pO1[i] = *(const uint4*)(w + i*8);
  };

  // ---- flag-vector barrier (R6-proven; no stager inside) ----
  unsigned int barcount = 0;
  auto gbar = [&]() {
    __syncthreads();
    ++barcount;
    if (tid == 0)
      __hip_atomic_store(flg + s*32, barcount, __ATOMIC_RELEASE, __HIP_MEMORY_SCOPE_AGENT);
    if (tid < GWG) {
      while (__hip_atomic_load(flg + tid*32, __ATOMIC_RELAXED, __HIP_MEMORY_SCOPE_AGENT) < barcount) {}
    }
    if (tid == 0)
      (void)__hip_atomic_load(flg + s*32, __ATOMIC_ACQUIRE, __HIP_MEMORY_SCOPE_AGENT);
    __syncthreads();
  };

  // ---- single-sync LN stats, per-site slots ----
  auto lnstats = [&](float v, float* slot, float& m, float& rs) {
    float a = v, b = v * v;
    #pragma unroll
    for (int off = 32; off; off >>= 1) { a += __shfl_xor(a, off); b += __shfl_xor(b, off); }
    if ((tid & 63) == 0 && tid < 256) { slot[tid >> 6] = a; slot[4 + (tid >> 6)] = b; }
    __syncthreads();
    float sa = slot[0]+slot[1]+slot[2]+slot[3];
    float sb = slot[4]+slot[5]+slot[6]+slot[7];
    m = sa * (1.0f/256.0f);
    rs = rsqrtf(sb * (1.0f/256.0f) - m*m + 1e-5f);
  };

  // ---- small params -> LDS ----
  for (int i = tid; i < 768; i += NTHR) {
    cals[i]  = CALW[i];
    obias[i] = p.sa_o_b[i];
    ff2b[i]  = p.ff2_b[i];
    ln1g[i] = p.ln1_g[i]; ln1b[i] = p.ln1_b[i];
    ln2g[i] = p.ln2_g[i]; ln2b[i] = p.ln2_b[i];
    ln3g[i] = p.ln3_g[i]; ln3b[i] = p.ln3_b[i];
  }
  for (int i = tid; i < 288; i += NTHR) {
    int l = i / 96, r = i % 96, sect = (r >> 5), o = r & 31;
    qkvb[i] = p.sa_qkv_b[l*768 + sect*256 + s*32 + o];
  }
  for (int i = tid; i < 384; i += NTHR) {
    int l = i >> 7, o = i & 127;
    ff1b[i] = p.ff1_b[l*1024 + s*128 + o];
  }
  for (int i = tid; i < DDIM*NOUT; i += NTHR) embw[i] = p.emb_w[i];
  for (int i = tid; i < DDIM; i += NTHR) embb[i] = p.emb_b[i];
  for (int i = tid; i < 128; i += NTHR) opb1[i] = p.op_b1[i];
  for (int i = tid; i < NOUT*128; i += NTHR) opw2[i] = p.op_w2[i];
  if (tid < NOUT) OUTV[tid] = p.start_token[tid];
  if (tid < 8) opb2[tid] = (tid < NOUT) ? p.op_b2[tid] : 0.f;

  const float divv = (tid < 256) ? expf(-0.035977892078031968f * (float)(2*(tid>>1))) : 0.f;
  __syncthreads();

  // prologue: x(t=0) + stage qkv(0) + WO(0)
  if (tid < 256) {
    float acc = embb[tid] + ((tid & 1) ? 1.0f : 0.0f);   // pe(t=0): sin0=0, cos0=1
    #pragma unroll
    for (int j = 0; j < NOUT; ++j) acc += OUTV[j] * embw[tid*NOUT + j];
    xls[tid] = acc;
  }
  stage_qkv(0);
  ldWO(0);
  __syncthreads();   // drains DMA + xls

  for (int t = 0; t < TSEQ; ++t) {
    for (int l = 0; l < NLAY; ++l) {
      // ================= PHASE Q =================
      if (l > 0) {
        float r2 = 0.f;
        if (tid < 256) {
          r2 = x2ls[tid] + ff2b[(l-1)*256 + tid];
          #pragma unroll
          for (int ss = 0; ss < GWG; ++ss) r2 += Pf[ss*256 + tid];
        }
        float m, rs; lnstats(r2, lred + 0, m, rs);
        if (tid < 256)
          xls[tid] = (r2 - m) * rs * ln3g[(l-1)*256 + tid] + ln3b[(l-1)*256 + tid];
        __syncthreads();
      }
      // qkv GEMV (staged LDS, 4 lanes/row, shuffle reduce)
      if (row < 96) {
        float acc = 0.f;
        #pragma unroll
        for (int i = 0; i < 8; ++i) {
          int ii = (i + kk) & 7;
          int k0 = kk*64 + ii*8;
          const uint4 w = *(const uint4*)(Rws + row*256 + (k0 ^ ((row&7)<<3)));
          acc += dot8(w, xls, k0);
        }
        acc += __shfl_xor(acc, 1);
        acc += __shfl_xor(acc, 2);
        if (kk == 0) {
          float v = acc + qkvb[l*96 + row];
          int sect = row >> 5, o = row & 31;
          if (sect == 0) qb[o] = v;
          else if (sect == 1) kc[(l*TSEQ + t)*33 + o] = v;
          else vc[(l*TSEQ + t)*33 + o] = v;
        }
      }
      __syncthreads();           // qkv Rws reads done; qb/kc/vc visible
      stage_ff1(l);              // async; drains by post-softmax sync (attn covers)
      // scores + softmax (wave 0 only -- other waves idle to next sync, R7-proven)
      if (tid < 64) {
        float scj = -1e30f;
        if (tid <= t) {
          const float* kr = &kc[(l*TSEQ + tid)*33];
          float a = 0.f;
          #pragma unroll
          for (int d = 0; d < HDIM; ++d) a += qb[d] * kr[d];
          scj = a * 0.17677669529663687f;
        }
        float mx = scj;
        #pragma unroll
        for (int off = 32; off; off >>= 1) mx = fmaxf(mx, __shfl_xor(mx, off));
        float e = (tid <= t) ? expf(scj - mx) : 0.f;
        float su = e;
        #pragma unroll
        for (int off = 32; off; off >>= 1) su += __shfl_xor(su, off);
        sc[tid] = e / su;
      }
      __syncthreads();
      // PV: 256 threads, 8 lanes per d
      if (tid < 256) {
        int d = tid >> 3, jg = tid & 7;
        float acc = 0.f;
        for (int j = jg; j <= t; j += 8) acc += sc[j] * vc[(l*TSEQ + j)*33 + d];
        acc += __shfl_xor(acc, 1);
        acc += __shfl_xor(acc, 2);
        acc += __shfl_xor(acc, 4);
        if (jg == 0) ah[d] = acc;
      }
      __syncthreads();
      // oproj partial (own head K-rows, register tile, 512 threads)
      red[tid] = dot8(pWO[0], ah, khB*16) + dot8(pWO[1], ah, khB*16 + 8);
      __syncthreads();
      if (tid < 256) Po[s*256 + tid] = red[tid] + red[tid + 256];
      gbar();   // B1

      // ================= PHASE F =================
      float r = 0.f;
      if (tid < 256) {
        r = xls[tid] + obias[l*256 + tid];
        #pragma unroll
        for (int ss = 0; ss < GWG; ++ss) r += Po[ss*256 + tid];
      }
      float m1, rs1; lnstats(r, lred + 8, m1, rs1);
      float z = 0.f;
      if (tid < 256)
        z = (r - m1)*rs1*ln1g[l*256 + tid] + ln1b[l*256 + tid] + cals[l*256 + tid];
      float m2, rs2; lnstats(z, lred + 16, m2, rs2);
      if (tid < 256) x2ls[tid] = (z - m2)*rs2*ln2g[l*256 + tid] + ln2b[l*256 + tid];
      __syncthreads();
      // ff1 GEMV (staged LDS, 4 lanes/row, shuffle reduce)
      float facc = 0.f;
      {
        #pragma unroll
        for (int i = 0; i < 8; ++i) {
          int ii = (i + kk) & 7;
          int k0 = kk*64 + ii*8;
          const uint4 w = *(const uint4*)(Rws + row*256 + (k0 ^ ((row&7)<<3)));
          facc += dot8(w, x2ls, k0);
        }
        facc += __shfl_xor(facc, 1);
        facc += __shfl_xor(facc, 2);
      }
      __syncthreads();             // all ff1 Rws reads done
      stage_ff2(l);                // async; gelu overlaps part of it
      if (kk == 0) fxl[row] = gelu_exact(facc + ff1b[l*128 + row]);
      __syncthreads();             // drains ff2 DMA + fxl visible
      // ff2 partial: thread (oB,khB) -> row oB, own 64-elem k-half (16-slot swizzle)
      {
        float acc = 0.f;
        #pragma unroll
        for (int j = 0; j < 8; ++j) {
          int k0 = khB*64 + j*8;
          const uint4 w = *(const uint4*)(Rws + oB*128 + (k0 ^ ((oB&15)<<3)));
          acc += dot8(w, fxl, k0);
        }
        red[tid] = acc;
      }
      __syncthreads();             // ff2 Rws reads done
      {
        int lnx = (l == 2) ? 0 : l + 1;
        stage_qkv(lnx);            // async; drains across B2
        ldWO(lnx);
        if (l == 2) ldO1();
      }
      if (tid < 256) Pf[s*256 + tid] = red[tid] + red[tid + 256];
      gbar();   // B2
    } // l

    // ============ STEP TAIL: ln3(l2) + output head + next-step x, all WGs ========
    {
      float r2 = 0.f;
      if (tid < 256) {
        r2 = x2ls[tid] + ff2b[2*256 + tid];
        #pragma unroll
        for (int ss = 0; ss < GWG; ++ss) r2 += Pf[ss*256 + tid];
      }
      float m, rs; lnstats(r2, lred + 24, m, rs);
      if (tid < 256) xls[tid] = (r2 - m)*rs*ln3g[2*256 + tid] + ln3b[2*256 + tid];
      __syncthreads();
      // op1 (register tile, 4 lanes/row, shuffle reduce)
      float oacc = 0.f;
      #pragma unroll
      for (int i = 0; i < 8; ++i) oacc += dot8(pO1[i], xls, kk*64 + i*8);
      oacc += __shfl_xor(oacc, 1);
      oacc += __shfl_xor(oacc, 2);
      if (kk == 0) fxl[row] = gelu_exact(oacc + opb1[row]);
      __syncthreads();
      // op2
      if (tid < 192) {
        int oo = tid >> 5, kl = tid & 31;
        float acc = fxl[kl]*opw2[oo*128 + kl] + fxl[kl+32]*opw2[oo*128 + kl+32]
                  + fxl[kl+64]*opw2[oo*128 + kl+64] + fxl[kl+96]*opw2[oo*128 + kl+96];
        #pragma unroll
        for (int off = 16; off; off >>= 1) acc += __shfl_xor(acc, off);
        if (kl == 0) {
          float v = acc + opb2[oo];
          OUTV[oo] = v;
          if (s == 0) p.out[((size_t)g*TSEQ + t)*NOUT + oo] = v;
        }
      }
      __syncthreads();
      // next-step x build (harmless at t=47)
      if (tid < 256) {
        float ang = (float)(t + 1) * divv;
        float pe = (tid & 1) ? cosf(ang) : sinf(ang);
        float acc = embb[tid] + pe;
        #pragma unroll
        for (int j = 0; j < NOUT; ++j) acc += OUTV[j] * embw[tid*NOUT + j];
        xls[tid] = acc;
      }
      __syncthreads();
    }
  } // t
}

extern "C" void kernel_launch(void* const* d_in, const int* in_sizes, int n_in,
                              void* d_out, int out_size, void* d_ws, size_t ws_size,
                              hipStream_t stream) {
  const float* const* F = (const float* const*)d_in;
  const float* z_style = F[0]; const float* z_skill = F[1];
  DecP p;
  p.start_token = F[2];
  const float* mem_w1 = F[3]; const float* mem_b1 = F[4];
  const float* mem_ln_g = F[5]; const float* mem_ln_b = F[6];
  const float* mem_w2 = F[7]; const float* mem_b2 = F[8];
  p.emb_w = F[9]; p.emb_b = F[10];
  const float* sa_qkv_w = F[11]; p.sa_qkv_b = F[12];
  const float* sa_o_w  = F[13]; p.sa_o_b = F[14];
  const float* ca_qkv_w = F[15]; const float* ca_qkv_b = F[16];
  const float* ca_o_w = F[17]; const float* ca_o_b = F[18];
  p.ln1_g = F[19]; p.ln1_b = F[20]; p.ln2_g = F[21]; p.ln2_b = F[22];
  p.ln3_g = F[23]; p.ln3_b = F[24];
  const float* ff1_w = F[25]; p.ff1_b = F[26];
  const float* ff2_w = F[27]; p.ff2_b = F[28];
  const float* op_w1 = F[29]; p.op_b1 = F[30]; p.op_w2 = F[31]; p.op_b2 = F[32];
  p.out = (float*)d_out;
  p.ws  = (unsigned char*)d_ws;

  hipMemsetAsync((char*)d_ws + CNT_OFF, 0, CNT_BYTES, stream);
  convert_bf16<<<dim3(512), dim3(256), 0, stream>>>(sa_qkv_w, sa_o_w, ff1_w, ff2_w, op_w1,
                                                    (unsigned char*)d_ws);
  precompute_ca<<<dim3(48), dim3(256), 0, stream>>>(z_style, z_skill, mem_w1, mem_b1,
                                                    mem_ln_g, mem_ln_b, mem_w2, mem_b2,
                                                    ca_qkv_w, ca_qkv_b, ca_o_w, ca_o_b,
                                                    (unsigned char*)d_ws);
  decoder_persistent<<<dim3(NBLK), dim3(NTHR), 0, stream>>>(p);
}

// Round 17
// 1965.692 us; speedup vs baseline: 4.0759x; 1.0360x over previous
//
#include <hip/hip_runtime.h>
#include <hip/hip_bf16.h>
#include <math.h>

// ---------------- problem constants ----------------
#define NGRP 16     // batch groups (one per batch element)
#define GWG  8      // workgroups per group (= heads)
#define NBLK (NGRP*GWG)   // 128
#define NTHR 512
#define TSEQ 48
#define DDIM 256
#define HDIM 32
#define NLAY 3
#define NOUT 6

// ---------------- ws layout ----------------
#define CNT_OFF   0u
#define CNT_BYTES 16384u         // 16 groups x 8 flag slots x 128B
#define GRP_OFF   16384u
#define GRP_STRF  5120u          // floats per group block
#define PO_F   0                 // [8*256] oproj partials
#define PF_F   2048              // [8*256] ff2 partials
#define CAL_F  4096              // [3*256] cross-attn constants
#define WB_OFF 360448u           // bf16 weights (element offsets below)
#define WOFF_QKV 0u
#define WOFF_WO  589824u
#define WOFF_F1  786432u
#define WOFF_F2  1572864u
#define WOFF_OP1 2359296u
#define NCVT     2392064u

typedef __attribute__((address_space(1))) const unsigned int gu32;
typedef __attribute__((address_space(3))) unsigned int lu32;

__device__ __forceinline__ void gl_lds16(const unsigned short* g, unsigned short* l) {
  __builtin_amdgcn_global_load_lds((gu32*)g, (lu32*)l, 16, 0, 0);
}
__device__ __forceinline__ void bfp(unsigned int u, float& lo, float& hi) {
  union { unsigned int i; float f; } a, b;
  a.i = u << 16; b.i = u & 0xffff0000u; lo = a.f; hi = b.f;
}
__device__ __forceinline__ float gelu_exact(float x) {
  return 0.5f * x * (1.0f + erff(x * 0.70710678118654752f));
}
__device__ __forceinline__ float dot8(const uint4& u, const float* x, int k0) {
  float lo, hi, acc = 0.f;
  bfp(u.x, lo, hi); acc += x[k0  ]*lo + x[k0+1]*hi;
  bfp(u.y, lo, hi); acc += x[k0+2]*lo + x[k0+3]*hi;
  bfp(u.z, lo, hi); acc += x[k0+4]*lo + x[k0+5]*hi;
  bfp(u.w, lo, hi); acc += x[k0+6]*lo + x[k0+7]*hi;
  return acc;
}

// ---------------- weight fp32 -> bf16 ----------------
__global__ void convert_bf16(const float* qkv, const float* ow, const float* f1,
                             const float* f2, const float* w1, unsigned char* ws) {
  __hip_bfloat16* dst = (__hip_bfloat16*)(ws + WB_OFF);
  size_t stride = (size_t)gridDim.x * blockDim.x;
  for (size_t i = (size_t)blockIdx.x * blockDim.x + threadIdx.x; i < NCVT; i += stride) {
    float v;
    if      (i < WOFF_WO)  v = qkv[i];
    else if (i < WOFF_F1)  v = ow[i - WOFF_WO];
    else if (i < WOFF_F2)  v = f1[i - WOFF_F1];
    else if (i < WOFF_OP1) v = f2[i - WOFF_F2];
    else                   v = w1[i - WOFF_OP1];
    dst[i] = __float2bfloat16(v);
  }
}

// ---------------- one-shot per-(g,l): memvec chain + cross-attn const ----------------
__global__ void precompute_ca(const float* zs, const float* zk,
                              const float* mw1, const float* mb1,
                              const float* mlg, const float* mlb,
                              const float* mw2, const float* mb2,
                              const float* cqw, const float* cqb,
                              const float* cow, const float* cob,
                              unsigned char* ws) {
  const int g = blockIdx.x & 15, l = blockIdx.x >> 4;
  const int tid = threadIdx.x;           // 256 threads
  __shared__ float cond[128], h[256], mvv[256], vv[256], lred[16];

  auto lnstat = [&](float v, float& m, float& rs) {
    float a = v, b = v * v;
    #pragma unroll
    for (int off = 32; off; off >>= 1) { a += __shfl_xor(a, off); b += __shfl_xor(b, off); }
    if ((tid & 63) == 0) { lred[tid >> 6] = a; lred[4 + (tid >> 6)] = b; }
    __syncthreads();
    float sa = lred[0]+lred[1]+lred[2]+lred[3];
    float sb = lred[4]+lred[5]+lred[6]+lred[7];
    m = sa * (1.0f/256.0f);
    rs = rsqrtf(sb * (1.0f/256.0f) - m*m + 1e-5f);
    __syncthreads();
  };

  if (tid < 128) cond[tid] = (tid < 64) ? zs[g*64 + tid] : zk[g*64 + tid - 64];
  __syncthreads();
  float acc = mb1[tid];
  { const float* w = mw1 + (size_t)tid * 128;
    for (int k = 0; k < 128; k += 4) {
      float4 q = *(const float4*)(w + k);
      acc += q.x*cond[k] + q.y*cond[k+1] + q.z*cond[k+2] + q.w*cond[k+3];
    } }
  float m, rs; lnstat(acc, m, rs);
  h[tid] = gelu_exact((acc - m) * rs * mlg[tid] + mlb[tid]);
  __syncthreads();
  float a2 = mb2[tid];
  { const float* w = mw2 + (size_t)tid * 256;
    for (int k = 0; k < 256; k += 4) {
      float4 q = *(const float4*)(w + k);
      a2 += q.x*h[k] + q.y*h[k+1] + q.z*h[k+2] + q.w*h[k+3];
    } }
  mvv[tid] = a2;
  __syncthreads();
  float a3 = cqb[l*768 + 512 + tid];
  { const float* w = cqw + ((size_t)l*768 + 512 + tid) * 256;
    for (int k = 0; k < 256; k += 4) {
      float4 q = *(const float4*)(w + k);
      a3 += q.x*mvv[k] + q.y*mvv[k+1] + q.z*mvv[k+2] + q.w*mvv[k+3];
    } }
  vv[tid] = a3;
  __syncthreads();
  float a4 = cob[l*256 + tid];
  { const float* w = cow + ((size_t)l*256 + tid) * 256;
    for (int k = 0; k < 256; k += 4) {
      float4 q = *(const float4*)(w + k);
      a4 += q.x*vv[k] + q.y*vv[k+1] + q.z*vv[k+2] + q.w*vv[k+3];
    } }
  ((float*)(ws + GRP_OFF))[(size_t)g * GRP_STRF + CAL_F + l*256 + tid] = a4;
}

struct DecP {
  const float *start_token, *emb_w, *emb_b;
  const float *sa_qkv_b, *sa_o_b;
  const float *ln1_g, *ln1_b, *ln2_g, *ln2_b, *ln3_g, *ln3_b;
  const float *ff1_b, *ff2_b;
  const float *op_b1, *op_w2, *op_b2;
  float* out;
  unsigned char* ws;
};

// Persistent decoder: R16 base (2036us) + intra-wave chain shortening:
// wave0-contained attention (softmax+PV), pair-lane shuffle oproj/ff2 (red[] deleted).
__global__ __launch_bounds__(NTHR, 1) void decoder_persistent(DecP p) {
  const int g = blockIdx.x % NGRP;
  const int s = blockIdx.x / NGRP;     // head / ff-slice id 0..7
  const int tid = threadIdx.x;

  unsigned int* flg = (unsigned int*)(p.ws + CNT_OFF) + (size_t)g * 256;  // 8 slots x 128B
  float* grp = (float*)(p.ws + GRP_OFF) + (size_t)g * GRP_STRF;
  float* Po = grp + PO_F;
  float* Pf = grp + PF_F;
  const float* CALW = grp + CAL_F;
  const unsigned short* WB = (const unsigned short*)(p.ws + WB_OFF);

  __shared__ __align__(16) unsigned short Rws[32768];   // 64KB weight stage region
  __shared__ float xls[DDIM], x2ls[DDIM], lred[32], fxl[128];
  __shared__ float qb[HDIM], ah[HDIM], sc[64];
  __shared__ float kc[NLAY*TSEQ*33], vc[NLAY*TSEQ*33];   // padded stride 33
  __shared__ float cals[768], obias[768], ff2b[768];
  __shared__ float ln1g[768], ln1b[768], ln2g[768], ln2b[768], ln3g[768], ln3b[768];
  __shared__ float qkvb[288], ff1b[384];
  __shared__ float embw[DDIM*NOUT], embb[DDIM];
  __shared__ float opb1[128], opw2[NOUT*128], opb2[8], OUTV[8];

  const int row = tid >> 2, kk = tid & 3;    // 4 threads per GEMV output row
  const int rw2 = tid >> 1, kh2 = tid & 1;   // pair-lane mapping (oproj/ff2)
  const int wv = tid >> 6, ln = tid & 63;    // wave id / lane id

  // ---- weight staging (async DMA; swizzled source gather, linear LDS dest) ----
  auto stage_qkv = [&](int l) {     // 96 rows x 512B, 8-slot swizzle
    #pragma unroll
    for (int r = 0; r < 6; ++r) {
      int c = (r*8 + wv)*64 + ln;
      int rw = c >> 5, wc = (c & 31) ^ (rw & 7);
      const unsigned short* gp = WB + WOFF_QKV
        + ((size_t)(l*768 + (rw>>5)*256 + s*32 + (rw&31)))*256 + wc*8;
      gl_lds16(gp, Rws + (size_t)(r*8 + wv)*512);
    }
  };
  auto stage_ff1 = [&](int l) {     // 128 rows x 512B, 8-slot swizzle
    #pragma unroll
    for (int r = 0; r < 8; ++r) {
      int c = (r*8 + wv)*64 + ln;
      int rw = c >> 5, wc = (c & 31) ^ (rw & 7);
      const unsigned short* gp = WB + WOFF_F1
        + ((size_t)(l*1024 + s*128 + rw))*256 + wc*8;
      gl_lds16(gp, Rws + (size_t)(r*8 + wv)*512);
    }
  };
  auto stage_ff2 = [&](int l) {     // 256 rows x 256B, 16-slot swizzle
    #pragma unroll
    for (int r = 0; r < 8; ++r) {
      int c = (r*8 + wv)*64 + ln;
      int rw = c >> 4, wc = (c & 15) ^ (rw & 15);
      const unsigned short* gp = WB + WOFF_F2
        + ((size_t)(l*256 + rw))*1024 + s*128 + wc*8;
      gl_lds16(gp, Rws + (size_t)(r*8 + wv)*512);
    }
  };

  // ---- small register tiles ----
  uint4 pWO[2], pO1[8];
  auto ldWO = [&](int l) {         // o-proj row rw2, k-half kh2 of own head (pair-lane)
    const unsigned short* w = WB + WOFF_WO + ((size_t)(l*256 + rw2))*256 + s*32 + kh2*16;
    pWO[0] = *(const uint4*)(w);
    pWO[1] = *(const uint4*)(w + 8);
  };
  auto ldO1 = [&]() {              // op_w1 rows (row, kk quarter)
    const unsigned short* w = WB + WOFF_OP1 + (size_t)row*256 + kk*64;
    #pragma unroll
    for (int i = 0; i < 8; ++i) pO1[i] = *(const uint4*)(w + i*8);
  };

  // ---- flag-vector barrier (R6-proven; no stager inside) ----
  unsigned int barcount = 0;
  auto gbar = [&]() {
    __syncthreads();
    ++barcount;
    if (tid == 0)
      __hip_atomic_store(flg + s*32, barcount, __ATOMIC_RELEASE, __HIP_MEMORY_SCOPE_AGENT);
    if (tid < GWG) {
      while (__hip_atomic_load(flg + tid*32, __ATOMIC_RELAXED, __HIP_MEMORY_SCOPE_AGENT) < barcount) {}
    }
    if (tid == 0)
      (void)__hip_atomic_load(flg + s*32, __ATOMIC_ACQUIRE, __HIP_MEMORY_SCOPE_AGENT);
    __syncthreads();
  };

  // ---- single-sync LN stats, per-site slots ----
  auto lnstats = [&](float v, float* slot, float& m, float& rs) {
    float a = v, b = v * v;
    #pragma unroll
    for (int off = 32; off; off >>= 1) { a += __shfl_xor(a, off); b += __shfl_xor(b, off); }
    if ((tid & 63) == 0 && tid < 256) { slot[tid >> 6] = a; slot[4 + (tid >> 6)] = b; }
    __syncthreads();
    float sa = slot[0]+slot[1]+slot[2]+slot[3];
    float sb = slot[4]+slot[5]+slot[6]+slot[7];
    m = sa * (1.0f/256.0f);
    rs = rsqrtf(sb * (1.0f/256.0f) - m*m + 1e-5f);
  };

  // ---- small params -> LDS ----
  for (int i = tid; i < 768; i += NTHR) {
    cals[i]  = CALW[i];
    obias[i] = p.sa_o_b[i];
    ff2b[i]  = p.ff2_b[i];
    ln1g[i] = p.ln1_g[i]; ln1b[i] = p.ln1_b[i];
    ln2g[i] = p.ln2_g[i]; ln2b[i] = p.ln2_b[i];
    ln3g[i] = p.ln3_g[i]; ln3b[i] = p.ln3_b[i];
  }
  for (int i = tid; i < 288; i += NTHR) {
    int l = i / 96, r = i % 96, sect = (r >> 5), o = r & 31;
    qkvb[i] = p.sa_qkv_b[l*768 + sect*256 + s*32 + o];
  }
  for (int i = tid; i < 384; i += NTHR) {
    int l = i >> 7, o = i & 127;
    ff1b[i] = p.ff1_b[l*1024 + s*128 + o];
  }
  for (int i = tid; i < DDIM*NOUT; i += NTHR) embw[i] = p.emb_w[i];
  for (int i = tid; i < DDIM; i += NTHR) embb[i] = p.emb_b[i];
  for (int i = tid; i < 128; i += NTHR) opb1[i] = p.op_b1[i];
  for (int i = tid; i < NOUT*128; i += NTHR) opw2[i] = p.op_w2[i];
  if (tid < NOUT) OUTV[tid] = p.start_token[tid];
  if (tid < 8) opb2[tid] = (tid < NOUT) ? p.op_b2[tid] : 0.f;

  const float divv = (tid < 256) ? expf(-0.035977892078031968f * (float)(2*(tid>>1))) : 0.f;
  __syncthreads();

  // prologue: x(t=0) + stage qkv(0) + WO(0)
  if (tid < 256) {
    float acc = embb[tid] + ((tid & 1) ? 1.0f : 0.0f);   // pe(t=0): sin0=0, cos0=1
    #pragma unroll
    for (int j = 0; j < NOUT; ++j) acc += OUTV[j] * embw[tid*NOUT + j];
    xls[tid] = acc;
  }
  stage_qkv(0);
  ldWO(0);
  __syncthreads();   // drains DMA + xls

  for (int t = 0; t < TSEQ; ++t) {
    for (int l = 0; l < NLAY; ++l) {
      // ================= PHASE Q =================
      if (l > 0) {
        float r2 = 0.f;
        if (tid < 256) {
          r2 = x2ls[tid] + ff2b[(l-1)*256 + tid];
          #pragma unroll
          for (int ss = 0; ss < GWG; ++ss) r2 += Pf[ss*256 + tid];
        }
        float m, rs; lnstats(r2, lred + 0, m, rs);
        if (tid < 256)
          xls[tid] = (r2 - m) * rs * ln3g[(l-1)*256 + tid] + ln3b[(l-1)*256 + tid];
        __syncthreads();
      }
      // qkv GEMV (staged LDS, 4 lanes/row, shuffle reduce)
      if (row < 96) {
        float acc = 0.f;
        #pragma unroll
        for (int i = 0; i < 8; ++i) {
          int ii = (i + kk) & 7;
          int k0 = kk*64 + ii*8;
          const uint4 w = *(const uint4*)(Rws + row*256 + (k0 ^ ((row&7)<<3)));
          acc += dot8(w, xls, k0);
        }
        acc += __shfl_xor(acc, 1);
        acc += __shfl_xor(acc, 2);
        if (kk == 0) {
          float v = acc + qkvb[l*96 + row];
          int sect = row >> 5, o = row & 31;
          if (sect == 0) qb[o] = v;
          else if (sect == 1) kc[(l*TSEQ + t)*33 + o] = v;
          else vc[(l*TSEQ + t)*33 + o] = v;
        }
      }
      __syncthreads();           // qkv Rws reads done; qb/kc/vc visible
      stage_ff1(l);              // async; drains by the post-attention sync
      // attention fully in wave 0: scores + softmax + PV (in-wave DS handoff)
      if (tid < 64) {
        float scj = -1e30f;
        if (tid <= t) {
          const float* kr = &kc[(l*TSEQ + tid)*33];
          float a = 0.f;
          #pragma unroll
          for (int d = 0; d < HDIM; ++d) a += qb[d] * kr[d];
          scj = a * 0.17677669529663687f;
        }
        float mx = scj;
        #pragma unroll
        for (int off = 32; off; off >>= 1) mx = fmaxf(mx, __shfl_xor(mx, off));
        float e = (tid <= t) ? expf(scj - mx) : 0.f;
        float su = e;
        #pragma unroll
        for (int off = 32; off; off >>= 1) su += __shfl_xor(su, off);
        sc[tid] = e / su;        // in-wave DS write; ordered vs reads below
        __builtin_amdgcn_wave_barrier();   // compiler fence (no reordering)
        // PV: 2 lanes per d (d = tid>>1, jg = tid&1), shuffle combine
        int d = tid >> 1, jg = tid & 1;
        float acc = 0.f;
        for (int j = jg; j <= t; j += 2) acc += sc[j] * vc[(l*TSEQ + j)*33 + d];
        acc += __shfl_xor(acc, 1);
        if (jg == 0) ah[d] = acc;
      }
      __syncthreads();           // ah visible to all; stage_ff1 DMA drained
      // oproj: pair-lane (row rw2, k-half kh2), shuffle combine -> Po direct
      {
        float acc = dot8(pWO[0], ah, kh2*16) + dot8(pWO[1], ah, kh2*16 + 8);
        acc += __shfl_xor(acc, 1);
        if (kh2 == 0) Po[s*256 + rw2] = acc;
      }
      gbar();   // B1

      // ================= PHASE F =================
      float r = 0.f;
      if (tid < 256) {
        r = xls[tid] + obias[l*256 + tid];
        #pragma unroll
        for (int ss = 0; ss < GWG; ++ss) r += Po[ss*256 + tid];
      }
      float m1, rs1; lnstats(r, lred + 8, m1, rs1);
      float z = 0.f;
      if (tid < 256)
        z = (r - m1)*rs1*ln1g[l*256 + tid] + ln1b[l*256 + tid] + cals[l*256 + tid];
      float m2, rs2; lnstats(z, lred + 16, m2, rs2);
      if (tid < 256) x2ls[tid] = (z - m2)*rs2*ln2g[l*256 + tid] + ln2b[l*256 + tid];
      __syncthreads();
      // ff1 GEMV (staged LDS, 4 lanes/row, shuffle reduce)
      float facc = 0.f;
      {
        #pragma unroll
        for (int i = 0; i < 8; ++i) {
          int ii = (i + kk) & 7;
          int k0 = kk*64 + ii*8;
          const uint4 w = *(const uint4*)(Rws + row*256 + (k0 ^ ((row&7)<<3)));
          facc += dot8(w, x2ls, k0);
        }
        facc += __shfl_xor(facc, 1);
        facc += __shfl_xor(facc, 2);
      }
      __syncthreads();             // all ff1 Rws reads done
      stage_ff2(l);                // async; gelu overlaps part of it
      if (kk == 0) fxl[row] = gelu_exact(facc + ff1b[l*128 + row]);
      __syncthreads();             // drains ff2 DMA + fxl visible
      // ff2: pair-lane (row rw2, k-half kh2), shuffle combine -> Pf direct
      {
        float acc = 0.f;
        #pragma unroll
        for (int j = 0; j < 8; ++j) {
          int k0 = kh2*64 + j*8;
          const uint4 w = *(const uint4*)(Rws + rw2*128 + (k0 ^ ((rw2&15)<<3)));
          acc += dot8(w, fxl, k0);
        }
        acc += __shfl_xor(acc, 1);
        if (kh2 == 0) Pf[s*256 + rw2] = acc;
      }
      __syncthreads();             // ff2 Rws reads done (before qkv DMA overwrites)
      {
        int lnx = (l == 2) ? 0 : l + 1;
        stage_qkv(lnx);            // async; drains across B2
        ldWO(lnx);
        if (l == 2) ldO1();
      }
      gbar();   // B2
    } // l

    // ============ STEP TAIL: ln3(l2) + output head + next-step x, all WGs ========
    {
      float r2 = 0.f;
      if (tid < 256) {
        r2 = x2ls[tid] + ff2b[2*256 + tid];
        #pragma unroll
        for (int ss = 0; ss < GWG; ++ss) r2 += Pf[ss*256 + tid];
      }
      float m, rs; lnstats(r2, lred + 24, m, rs);
      if (tid < 256) xls[tid] = (r2 - m)*rs*ln3g[2*256 + tid] + ln3b[2*256 + tid];
      __syncthreads();
      // op1 (register tile, 4 lanes/row, shuffle reduce)
      float oacc = 0.f;
      #pragma unroll
      for (int i = 0; i < 8; ++i) oacc += dot8(pO1[i], xls, kk*64 + i*8);
      oacc += __shfl_xor(oacc, 1);
      oacc += __shfl_xor(oacc, 2);
      if (kk == 0) fxl[row] = gelu_exact(oacc + opb1[row]);
      __syncthreads();
      // op2
      if (tid < 192) {
        int oo = tid >> 5, kl = tid & 31;
        float acc = fxl[kl]*opw2[oo*128 + kl] + fxl[kl+32]*opw2[oo*128 + kl+32]
                  + fxl[kl+64]*opw2[oo*128 + kl+64] + fxl[kl+96]*opw2[oo*128 + kl+96];
        #pragma unroll
        for (int off = 16; off; off >>= 1) acc += __shfl_xor(acc, off);
        if (kl == 0) {
          float v = acc + opb2[oo];
          OUTV[oo] = v;
          if (s == 0) p.out[((size_t)g*TSEQ + t)*NOUT + oo] = v;
        }
      }
      __syncthreads();
      // next-step x build (harmless at t=47)
      if (tid < 256) {
        float ang = (float)(t + 1) * divv;
        float pe = (tid & 1) ? cosf(ang) : sinf(ang);
        float acc = embb[tid] + pe;
        #pragma unroll
        for (int j = 0; j < NOUT; ++j) acc += OUTV[j] * embw[tid*NOUT + j];
        xls[tid] = acc;
      }
      __syncthreads();
    }
  } // t
}

extern "C" void kernel_launch(void* const* d_in, const int* in_sizes, int n_in,
                              void* d_out, int out_size, void* d_ws, size_t ws_size,
                              hipStream_t stream) {
  const float* const* F = (const float* const*)d_in;
  const float* z_style = F[0]; const float* z_skill = F[1];
  DecP p;
  p.start_token = F[2];
  const float* mem_w1 = F[3]; const float* mem_b1 = F[4];
  const float* mem_ln_g = F[5]; const float* mem_ln_b = F[6];
  const float* mem_w2 = F[7]; const float* mem_b2 = F[8];
  p.emb_w = F[9]; p.emb_b = F[10];
  const float* sa_qkv_w = F[11]; p.sa_qkv_b = F[12];
  const float* sa_o_w  = F[13]; p.sa_o_b = F[14];
  const float* ca_qkv_w = F[15]; const float* ca_qkv_b = F[16];
  const float* ca_o_w = F[17]; const float* ca_o_b = F[18];
  p.ln1_g = F[19]; p.ln1_b = F[20]; p.ln2_g = F[21]; p.ln2_b = F[22];
  p.ln3_g = F[23]; p.ln3_b = F[24];
  const float* ff1_w = F[25]; p.ff1_b = F[26];
  const float* ff2_w = F[27]; p.ff2_b = F[28];
  const float* op_w1 = F[29]; p.op_b1 = F[30]; p.op_w2 = F[31]; p.op_b2 = F[32];
  p.out = (float*)d_out;
  p.ws  = (unsigned char*)d_ws;

  hipMemsetAsync((char*)d_ws + CNT_OFF, 0, CNT_BYTES, stream);
  convert_bf16<<<dim3(512), dim3(256), 0, stream>>>(sa_qkv_w, sa_o_w, ff1_w, ff2_w, op_w1,
                                                    (unsigned char*)d_ws);
  precompute_ca<<<dim3(48), dim3(256), 0, stream>>>(z_style, z_skill, mem_w1, mem_b1,
                                                    mem_ln_g, mem_ln_b, mem_w2, mem_b2,
                                                    ca_qkv_w, ca_qkv_b, ca_o_w, ca_o_b,
                                                    (unsigned char*)d_ws);
  decoder_persistent<<<dim3(NBLK), dim3(NTHR), 0, stream>>>(p);
}